// Round 5
// baseline (272.995 us; speedup 1.0000x reference)
//
#include <hip/hip_runtime.h>

typedef __bf16 bf16;
typedef short s16x8 __attribute__((ext_vector_type(8)));   // 8 bf16 bit-patterns for MFMA frags
typedef __bf16 b16x8 __attribute__((ext_vector_type(8)));  // 8 bf16 for scalar convert paths
typedef float f32x4 __attribute__((ext_vector_type(4)));

#define B_   4096
#define L_   50
#define SX   136   // Xs row stride (bf16): 128 + 8 pad (272 B rows, 16B aligned)

// ws layout (bf16 elems unless noted)
#define OFF_W1T  0        // [64][128]  gv_w1^T
#define OFF_W2T  8192     // [64][64]   gv_w2^T
#define OFF_W3T  12288    // [64][64]   gv_w3^T
#define OFF_WCAT 16384    // [64][128]  [W3@A1_top ; A1_bot]^T
#define OFF_A2T  24576    // [64][64]   att_w2^T
#define OFF_R1T  28672    // [64][128]  wr1^T
#define OFF_R2T  36864    // [64][64]   wr2^T
#define WT_TOTAL 40960
#define BIAS1P_BYTE 81920 // float[64]  gv_b3@A1_top + att_b1

__device__ __forceinline__ unsigned short f2b(float f) {
    __bf16 h = (__bf16)f;
    return __builtin_bit_cast(unsigned short, h);
}
__device__ __forceinline__ unsigned pack2(float a, float b) {
    return (unsigned)f2b(a) | ((unsigned)f2b(b) << 16);
}

// O = act(A @ W + bias): 16 rows x 64 cols per wave. A in LDS (stride sA), Wt[n][k] global bf16.
// HW-verified layouts: A[m=lane&15][k=quad*8+j]; B[k=quad*8+j][n=lane&15]; D col=lane&15, row=quad*4+reg.
// Same-wave LDS WAR/RAW (O0 overlapping A0) is safe: per-wave DS pipe is in-order.
template<int KT, bool RELU>
__device__ __forceinline__ void layer(const bf16* A0, int sA,
                                      const bf16* __restrict__ Wt, const float* __restrict__ bias,
                                      bf16* O0, int sO, int lane)
{
    const int m = lane & 15, quad = lane >> 4;
    f32x4 acc[4] = {};
#pragma unroll
    for (int kt = 0; kt < KT; ++kt) {
        s16x8 a = *(const s16x8*)(A0 + m * sA + kt * 32 + quad * 8);
#pragma unroll
        for (int nt = 0; nt < 4; ++nt) {
            s16x8 b = *(const s16x8*)(Wt + (nt * 16 + m) * (KT * 32) + kt * 32 + quad * 8);
            acc[nt] = __builtin_amdgcn_mfma_f32_16x16x32_bf16(a, b, acc[nt], 0, 0, 0);
        }
    }
#pragma unroll
    for (int nt = 0; nt < 4; ++nt) {
        int c = nt * 16 + m;
        float bv = bias[c];
#pragma unroll
        for (int r4 = 0; r4 < 4; ++r4) {
            float v = acc[nt][r4] + bv;
            if (RELU) v = fmaxf(v, 0.f);
            O0[(quad * 4 + r4) * sO + c] = (bf16)v;
        }
    }
}

// ---------------- prep: bf16 transposed weights, WCAT fold, bias1' ----------------
extern "C" __global__ void prep_weights(const float* __restrict__ w1, const float* __restrict__ w2,
                                        const float* __restrict__ w3, const float* __restrict__ a1,
                                        const float* __restrict__ a2, const float* __restrict__ r1,
                                        const float* __restrict__ r2, const float* __restrict__ gb3,
                                        const float* __restrict__ ab1,
                                        bf16* __restrict__ wt, float* __restrict__ bias1p)
{
    int i = blockIdx.x * blockDim.x + threadIdx.x;
    if (i >= WT_TOTAL + 64) return;
    if (i >= WT_TOTAL) {                       // bias1'[n] = ab1[n] + sum_t gb3[t]*a1[t][n]
        int n = i - WT_TOTAL;
        float s0 = ab1[n], s1 = 0.f, s2 = 0.f, s3 = 0.f;
#pragma unroll
        for (int t = 0; t < 64; t += 4) {
            s0 = fmaf(gb3[t],     a1[t * 64 + n],       s0);
            s1 = fmaf(gb3[t + 1], a1[(t + 1) * 64 + n], s1);
            s2 = fmaf(gb3[t + 2], a1[(t + 2) * 64 + n], s2);
            s3 = fmaf(gb3[t + 3], a1[(t + 3) * 64 + n], s3);
        }
        bias1p[n] = (s0 + s1) + (s2 + s3);
        return;
    }
    float val;
    if (i < OFF_W2T)       { int li = i;            int n = li >> 7, k = li & 127; val = w1[k * 64 + n]; }
    else if (i < OFF_W3T)  { int li = i - OFF_W2T;  int n = li >> 6, k = li & 63;  val = w2[k * 64 + n]; }
    else if (i < OFF_WCAT) { int li = i - OFF_W3T;  int n = li >> 6, k = li & 63;  val = w3[k * 64 + n]; }
    else if (i < OFF_A2T)  {                        // WCAT[n][k]
        int li = i - OFF_WCAT; int n = li >> 7, k = li & 127;
        if (k >= 64) val = a1[k * 64 + n];          // A1_bot
        else {                                      // (W3 @ A1_top)[k][n]
            float s0 = 0.f, s1 = 0.f, s2 = 0.f, s3 = 0.f;
#pragma unroll
            for (int t = 0; t < 64; t += 4) {
                float4 w = *(const float4*)(w3 + k * 64 + t);
                s0 = fmaf(w.x, a1[t * 64 + n],       s0);
                s1 = fmaf(w.y, a1[(t + 1) * 64 + n], s1);
                s2 = fmaf(w.z, a1[(t + 2) * 64 + n], s2);
                s3 = fmaf(w.w, a1[(t + 3) * 64 + n], s3);
            }
            val = (s0 + s1) + (s2 + s3);
        }
    }
    else if (i < OFF_R1T)  { int li = i - OFF_A2T;  int n = li >> 6, k = li & 63;  val = a2[k * 64 + n]; }
    else if (i < OFF_R2T)  { int li = i - OFF_R1T;  int n = li >> 7, k = li & 127; val = r1[k * 64 + n]; }
    else                   { int li = i - OFF_R2T;  int n = li >> 6, k = li & 63;  val = r2[k * 64 + n]; }
    wt[i] = (bf16)val;
}

// ---------------- fully fused main: gather -> 5 layers -> softmax -> zj -> combine -> out ----------------
// launch_bounds (256,6): 6 waves/EU -> reg budget ~85/lane (VGPR+AGPR unified).
// (256,8) forced a 64-reg cap -> 32 arch VGPRs + 144 MB scratch spill (round-4 counters). 6 fits the
// measured ~64-80 need with zero spill; LDS 19.2 KB caps at 8 so we're reg-bound at 6 blocks/CU.
extern "C" __global__ void __launch_bounds__(256, 6)
item_main(const int* __restrict__ nodes_v, const int* __restrict__ neigh_u,
          const int* __restrict__ neigh_r,
          const float* __restrict__ embed_u, const float* __restrict__ embed_i,
          const float* __restrict__ embed_r,
          const float* __restrict__ gv_b1, const float* __restrict__ gv_b2,
          const float* __restrict__ gv_b3,
          const float* __restrict__ att_b2, const float* __restrict__ att_w3,
          const float* __restrict__ wr1_b, const float* __restrict__ wr2_b,
          const bf16* __restrict__ wt, const float* __restrict__ bias1p,
          float* __restrict__ out)
{
    __shared__ __align__(16) bf16 Xs[64 * SX];
    __shared__ float qs[64];      // q (f32) for the combine tail
    __shared__ float scs[64];     // attention scores; reused as z2 in tail
    __shared__ float muS[64];     // zj share in tail
    __shared__ float zp[4 * 64];  // zj partials

    const int b = blockIdx.x;
    const int tid = threadIdx.x;
    const int lane = tid & 63, wave = tid >> 6;
    const int m = lane & 15, quad = lane >> 4;
    const int rb = wave * 16;
    const int v = nodes_v[b];

    // q A-frags in regs (row-broadcast): qf[t][j] = q[t*32 + quad*8 + j]
    s16x8 qf[2];
#pragma unroll
    for (int t = 0; t < 2; ++t) {
        float4 qa = *(const float4*)(embed_i + v * 64 + t * 32 + quad * 8);
        float4 qb4 = *(const float4*)(embed_i + v * 64 + t * 32 + quad * 8 + 4);
        s16x8 r;
        r[0] = (short)f2b(qa.x);  r[1] = (short)f2b(qa.y);  r[2] = (short)f2b(qa.z);  r[3] = (short)f2b(qa.w);
        r[4] = (short)f2b(qb4.x); r[5] = (short)f2b(qb4.y); r[6] = (short)f2b(qb4.z); r[7] = (short)f2b(qb4.w);
        qf[t] = r;
    }
    if (tid < 64) qs[tid] = embed_i[v * 64 + tid];

    // wave-local gather: wave w stages rows [rb, rb+16); pt -> X[:,0:64], er -> X[:,64:128]
    {
        const int rsub = lane >> 4;   // 4 rows per iter
        const int c = lane & 15;      // 16B chunk (4 floats)
#pragma unroll
        for (int it = 0; it < 4; ++it) {
            int row = rb + it * 4 + rsub;
            float4 vu = make_float4(0.f, 0.f, 0.f, 0.f), vr = vu;
            if (row < L_) {
                int u = neigh_u[b * L_ + row];
                int r = neigh_r[b * L_ + row];
                vu = *(const float4*)(embed_u + u * 64 + c * 4);
                vr = *(const float4*)(embed_r + r * 64 + c * 4);
            }
            uint2 pu, pr;
            pu.x = pack2(vu.x, vu.y); pu.y = pack2(vu.z, vu.w);
            pr.x = pack2(vr.x, vr.y); pr.y = pack2(vr.z, vr.w);
            *(uint2*)(Xs + row * SX + c * 4) = pu;
            *(uint2*)(Xs + row * SX + 64 + c * 4) = pr;
        }
    }

    const bf16* w1t = wt + OFF_W1T;
    const bf16* w2t = wt + OFF_W2T;
    const bf16* w3t = wt + OFF_W3T;
    const bf16* wct = wt + OFF_WCAT;
    const bf16* a2t = wt + OFF_A2T;

    bf16* Xw = Xs + rb * SX;   // this wave's 16-row tile

    // gv1: X[:,0:128] -> h1 -> X[:,64:128]   (er dead after reads; same-wave WAR safe)
    layer<4, true>(Xw, SX, w1t, gv_b1, Xw + 64, SX, lane);
    // gv2: X[:,64:128] -> h2 -> X[:,0:64]
    layer<2, true>(Xw + 64, SX, w2t, gv_b2, Xw, SX, lane);

    // fused gv3 + att1': consume h2; fjt -> X[:,64:128], att1h -> X[:,0:64]
    {
        f32x4 accF[4] = {}, accA[4] = {};
#pragma unroll
        for (int kt = 0; kt < 2; ++kt) {
            s16x8 a = *(const s16x8*)(Xw + m * SX + kt * 32 + quad * 8);
#pragma unroll
            for (int nt = 0; nt < 4; ++nt) {
                s16x8 bF = *(const s16x8*)(w3t + (nt * 16 + m) * 64 + kt * 32 + quad * 8);
                s16x8 bA = *(const s16x8*)(wct + (nt * 16 + m) * 128 + kt * 32 + quad * 8);
                accF[nt] = __builtin_amdgcn_mfma_f32_16x16x32_bf16(a, bF, accF[nt], 0, 0, 0);
                accA[nt] = __builtin_amdgcn_mfma_f32_16x16x32_bf16(a, bA, accA[nt], 0, 0, 0);
            }
        }
#pragma unroll
        for (int kt = 2; kt < 4; ++kt) {
#pragma unroll
            for (int nt = 0; nt < 4; ++nt) {
                s16x8 bA = *(const s16x8*)(wct + (nt * 16 + m) * 128 + kt * 32 + quad * 8);
                accA[nt] = __builtin_amdgcn_mfma_f32_16x16x32_bf16(qf[kt - 2], bA, accA[nt], 0, 0, 0);
            }
        }
#pragma unroll
        for (int nt = 0; nt < 4; ++nt) {
            int c = nt * 16 + m;
            float b3v = gv_b3[c], b1v = bias1p[c];
#pragma unroll
            for (int r4 = 0; r4 < 4; ++r4) {
                int ro = (quad * 4 + r4) * SX;
                Xw[ro + 64 + c] = (bf16)(accF[nt][r4] + b3v);         // fjt (no relu)
                Xw[ro + c] = (bf16)fmaxf(accA[nt][r4] + b1v, 0.f);    // att1h
            }
        }
    }

    // att2 in regs + relu + dot(att_w3) + 16-lane reduce -> scores
    {
        f32x4 acc[4] = {};
#pragma unroll
        for (int kt = 0; kt < 2; ++kt) {
            s16x8 a = *(const s16x8*)(Xw + m * SX + kt * 32 + quad * 8);
#pragma unroll
            for (int nt = 0; nt < 4; ++nt) {
                s16x8 bb = *(const s16x8*)(a2t + (nt * 16 + m) * 64 + kt * 32 + quad * 8);
                acc[nt] = __builtin_amdgcn_mfma_f32_16x16x32_bf16(a, bb, acc[nt], 0, 0, 0);
            }
        }
        float sc[4] = {0.f, 0.f, 0.f, 0.f};
#pragma unroll
        for (int nt = 0; nt < 4; ++nt) {
            int c = nt * 16 + m;
            float b2v = att_b2[c], w3v = att_w3[c];
#pragma unroll
            for (int r4 = 0; r4 < 4; ++r4)
                sc[r4] += fmaxf(acc[nt][r4] + b2v, 0.f) * w3v;
        }
#pragma unroll
        for (int mask = 1; mask < 16; mask <<= 1)
#pragma unroll
            for (int r4 = 0; r4 < 4; ++r4) sc[r4] += __shfl_xor(sc[r4], mask);
        if (m == 0) {
#pragma unroll
            for (int r4 = 0; r4 < 4; ++r4) scs[rb + quad * 4 + r4] = sc[r4];
        }
    }
    __syncthreads();   // scs + fjt visible to all

    // softmax computed redundantly per-wave (regs only, no barrier, all waves stay busy)
    // att_b3 dropped: softmax is shift-invariant.
    {
        float s = (lane < L_) ? scs[lane] : -1e30f;
        float mx = s;
#pragma unroll
        for (int off = 32; off; off >>= 1) mx = fmaxf(mx, __shfl_xor(mx, off));
        float e = (lane < L_) ? __expf(s - mx) : 0.f;
        float sum = e;
#pragma unroll
        for (int off = 32; off; off >>= 1) sum += __shfl_xor(sum, off);
        float mu = e / sum;   // lane holds mu[lane]

        // zj partial: wave w reduces its own 16 fjt rows; mu[l] via shuffle broadcast
        float z = 0.f;
#pragma unroll
        for (int i = 0; i < 16; ++i) {
            int l = rb + i;
            z += (float)Xs[l * SX + 64 + lane] * __shfl(mu, l);
        }
        zp[wave * 64 + lane] = z;
    }
    __syncthreads();

    // combine tail on wave 0: out = relu(relu([zj|q] @ wr1 + b1) @ wr2 + b2)
    if (wave == 0) {
        float z = zp[lane] + zp[64 + lane] + zp[128 + lane] + zp[192 + lane];
        muS[lane] = z;   // share zj (same-wave in-order)

        float accz = wr1_b[lane];
        const bf16* r1 = wt + OFF_R1T + lane * 128;
#pragma unroll
        for (int k8 = 0; k8 < 8; ++k8) {
            b16x8 wv = *(const b16x8*)(r1 + k8 * 8);
#pragma unroll
            for (int j = 0; j < 8; ++j) accz = fmaf((float)wv[j], muS[k8 * 8 + j], accz);
        }
#pragma unroll
        for (int k8 = 0; k8 < 8; ++k8) {
            b16x8 wv = *(const b16x8*)(r1 + 64 + k8 * 8);
#pragma unroll
            for (int j = 0; j < 8; ++j) accz = fmaf((float)wv[j], qs[k8 * 8 + j], accz);
        }
        accz = fmaxf(accz, 0.f);
        scs[lane] = accz;   // share z2 (same-wave in-order)

        float acco = wr2_b[lane];
        const bf16* r2 = wt + OFF_R2T + lane * 64;
#pragma unroll
        for (int k8 = 0; k8 < 8; ++k8) {
            b16x8 wv = *(const b16x8*)(r2 + k8 * 8);
#pragma unroll
            for (int j = 0; j < 8; ++j) acco = fmaf((float)wv[j], scs[k8 * 8 + j], acco);
        }
        out[b * 64 + lane] = fmaxf(acco, 0.f);
    }
}

extern "C" void kernel_launch(void* const* d_in, const int* in_sizes, int n_in,
                              void* d_out, int out_size, void* d_ws, size_t ws_size,
                              hipStream_t stream)
{
    const int* nodes_v = (const int*)d_in[0];
    const int* neigh_u = (const int*)d_in[1];
    const int* neigh_r = (const int*)d_in[2];
    const float* embed_u = (const float*)d_in[3];
    const float* embed_i = (const float*)d_in[4];
    const float* embed_r = (const float*)d_in[5];
    const float* gv_w1  = (const float*)d_in[6];  const float* gv_b1 = (const float*)d_in[7];
    const float* gv_w2  = (const float*)d_in[8];  const float* gv_b2 = (const float*)d_in[9];
    const float* gv_w3  = (const float*)d_in[10]; const float* gv_b3 = (const float*)d_in[11];
    const float* att_w1 = (const float*)d_in[12]; const float* att_b1 = (const float*)d_in[13];
    const float* att_w2 = (const float*)d_in[14]; const float* att_b2 = (const float*)d_in[15];
    const float* att_w3 = (const float*)d_in[16]; const float* att_b3 = (const float*)d_in[17];
    const float* wr1_w  = (const float*)d_in[18]; const float* wr1_b = (const float*)d_in[19];
    const float* wr2_w  = (const float*)d_in[20]; const float* wr2_b = (const float*)d_in[21];
    (void)att_b3;

    bf16* wt      = (bf16*)d_ws;
    float* bias1p = (float*)((char*)d_ws + BIAS1P_BYTE);

    prep_weights<<<(WT_TOTAL + 64 + 255) / 256, 256, 0, stream>>>(
        gv_w1, gv_w2, gv_w3, att_w1, att_w2, wr1_w, wr2_w, gv_b3, att_b1, wt, bias1p);
    item_main<<<B_, 256, 0, stream>>>(nodes_v, neigh_u, neigh_r, embed_u, embed_i, embed_r,
                                      gv_b1, gv_b2, gv_b3, att_b2, att_w3,
                                      wr1_b, wr2_b, wt, bias1p, (float*)d_out);
}

// Round 6
// 242.046 us; speedup vs baseline: 1.1279x; 1.1279x over previous
//
#include <hip/hip_runtime.h>

typedef __bf16 bf16;
typedef short s16x8 __attribute__((ext_vector_type(8)));   // 8 bf16 bit-patterns for MFMA frags
typedef __bf16 b16x8 __attribute__((ext_vector_type(8)));  // 8 bf16 for scalar convert paths
typedef float f32x4 __attribute__((ext_vector_type(4)));

#define B_   4096
#define L_   50
#define SX   136   // Xs row stride (bf16): 128 + 8 pad (272 B rows, 16B aligned)

// ws layout (bf16 elems unless noted)
#define OFF_W1T  0        // [64][128]  gv_w1^T
#define OFF_W2T  8192     // [64][64]   gv_w2^T
#define OFF_W3T  12288    // [64][64]   gv_w3^T
#define OFF_WCAT 16384    // [64][128]  [W3@A1_top ; A1_bot]^T
#define OFF_A2T  24576    // [64][64]   att_w2^T
#define OFF_R1T  28672    // [64][128]  wr1^T
#define OFF_R2T  36864    // [64][64]   wr2^T
#define WT_TOTAL 40960
#define BIAS1P_BYTE 81920 // float[64]  gv_b3@A1_top + att_b1

__device__ __forceinline__ unsigned short f2b(float f) {
    __bf16 h = (__bf16)f;
    return __builtin_bit_cast(unsigned short, h);
}
__device__ __forceinline__ unsigned pack2(float a, float b) {
    return (unsigned)f2b(a) | ((unsigned)f2b(b) << 16);
}

// O = act(A @ W + bias): 16 rows x 64 cols per wave. A in LDS (stride sA), Wt[n][k] global bf16.
// HW-verified layouts: A[m=lane&15][k=quad*8+j]; B[k=quad*8+j][n=lane&15]; D col=lane&15, row=quad*4+reg.
// Same-wave LDS WAR/RAW (O0 overlapping A0) is safe: per-wave DS pipe is in-order.
template<int KT, bool RELU>
__device__ __forceinline__ void layer(const bf16* A0, int sA,
                                      const bf16* __restrict__ Wt, const float* __restrict__ bias,
                                      bf16* O0, int sO, int lane)
{
    const int m = lane & 15, quad = lane >> 4;
    f32x4 acc[4] = {};
#pragma unroll
    for (int kt = 0; kt < KT; ++kt) {
        s16x8 a = *(const s16x8*)(A0 + m * sA + kt * 32 + quad * 8);
#pragma unroll
        for (int nt = 0; nt < 4; ++nt) {
            s16x8 b = *(const s16x8*)(Wt + (nt * 16 + m) * (KT * 32) + kt * 32 + quad * 8);
            acc[nt] = __builtin_amdgcn_mfma_f32_16x16x32_bf16(a, b, acc[nt], 0, 0, 0);
        }
    }
#pragma unroll
    for (int nt = 0; nt < 4; ++nt) {
        int c = nt * 16 + m;
        float bv = bias[c];
#pragma unroll
        for (int r4 = 0; r4 < 4; ++r4) {
            float v = acc[nt][r4] + bv;
            if (RELU) v = fmaxf(v, 0.f);
            O0[(quad * 4 + r4) * sO + c] = (bf16)v;
        }
    }
}

// ---------------- prep: bf16 transposed weights, WCAT fold, bias1' ----------------
extern "C" __global__ void prep_weights(const float* __restrict__ w1, const float* __restrict__ w2,
                                        const float* __restrict__ w3, const float* __restrict__ a1,
                                        const float* __restrict__ a2, const float* __restrict__ r1,
                                        const float* __restrict__ r2, const float* __restrict__ gb3,
                                        const float* __restrict__ ab1,
                                        bf16* __restrict__ wt, float* __restrict__ bias1p)
{
    int i = blockIdx.x * blockDim.x + threadIdx.x;
    if (i >= WT_TOTAL + 64) return;
    if (i >= WT_TOTAL) {                       // bias1'[n] = ab1[n] + sum_t gb3[t]*a1[t][n]
        int n = i - WT_TOTAL;
        float s0 = ab1[n], s1 = 0.f, s2 = 0.f, s3 = 0.f;
#pragma unroll
        for (int t = 0; t < 64; t += 4) {
            s0 = fmaf(gb3[t],     a1[t * 64 + n],       s0);
            s1 = fmaf(gb3[t + 1], a1[(t + 1) * 64 + n], s1);
            s2 = fmaf(gb3[t + 2], a1[(t + 2) * 64 + n], s2);
            s3 = fmaf(gb3[t + 3], a1[(t + 3) * 64 + n], s3);
        }
        bias1p[n] = (s0 + s1) + (s2 + s3);
        return;
    }
    float val;
    if (i < OFF_W2T)       { int li = i;            int n = li >> 7, k = li & 127; val = w1[k * 64 + n]; }
    else if (i < OFF_W3T)  { int li = i - OFF_W2T;  int n = li >> 6, k = li & 63;  val = w2[k * 64 + n]; }
    else if (i < OFF_WCAT) { int li = i - OFF_W3T;  int n = li >> 6, k = li & 63;  val = w3[k * 64 + n]; }
    else if (i < OFF_A2T)  {                        // WCAT[n][k]
        int li = i - OFF_WCAT; int n = li >> 7, k = li & 127;
        if (k >= 64) val = a1[k * 64 + n];          // A1_bot
        else {                                      // (W3 @ A1_top)[k][n]
            float s0 = 0.f, s1 = 0.f, s2 = 0.f, s3 = 0.f;
#pragma unroll
            for (int t = 0; t < 64; t += 4) {
                float4 w = *(const float4*)(w3 + k * 64 + t);
                s0 = fmaf(w.x, a1[t * 64 + n],       s0);
                s1 = fmaf(w.y, a1[(t + 1) * 64 + n], s1);
                s2 = fmaf(w.z, a1[(t + 2) * 64 + n], s2);
                s3 = fmaf(w.w, a1[(t + 3) * 64 + n], s3);
            }
            val = (s0 + s1) + (s2 + s3);
        }
    }
    else if (i < OFF_R1T)  { int li = i - OFF_A2T;  int n = li >> 6, k = li & 63;  val = a2[k * 64 + n]; }
    else if (i < OFF_R2T)  { int li = i - OFF_R1T;  int n = li >> 7, k = li & 127; val = r1[k * 64 + n]; }
    else                   { int li = i - OFF_R2T;  int n = li >> 6, k = li & 63;  val = r2[k * 64 + n]; }
    wt[i] = (bf16)val;
}

// ---------------- fully fused main: gather -> 5 layers -> softmax -> zj -> combine -> out ----------------
// __launch_bounds__(256,4): the compiler's VGPR budget is empirically 256/min_waves
// ((256,8)->32 regs+144MB spill, (256,6)->40 regs+79MB spill, (256,4)->64 regs NO spill).
// 64 arch VGPRs allows 8 waves/SIMD by the HW halving table, and LDS 19.2KB caps at 8 blocks/CU,
// so (256,4) still permits full residency — it just stops the allocator from spilling.
extern "C" __global__ void __launch_bounds__(256, 4)
item_main(const int* __restrict__ nodes_v, const int* __restrict__ neigh_u,
          const int* __restrict__ neigh_r,
          const float* __restrict__ embed_u, const float* __restrict__ embed_i,
          const float* __restrict__ embed_r,
          const float* __restrict__ gv_b1, const float* __restrict__ gv_b2,
          const float* __restrict__ gv_b3,
          const float* __restrict__ att_b2, const float* __restrict__ att_w3,
          const float* __restrict__ wr1_b, const float* __restrict__ wr2_b,
          const bf16* __restrict__ wt, const float* __restrict__ bias1p,
          float* __restrict__ out)
{
    __shared__ __align__(16) bf16 Xs[64 * SX];
    __shared__ float qs[64];      // q (f32) for the combine tail
    __shared__ float scs[64];     // attention scores; reused as z2 in tail
    __shared__ float muS[64];     // zj share in tail
    __shared__ float zp[4 * 64];  // zj partials

    const int b = blockIdx.x;
    const int tid = threadIdx.x;
    const int lane = tid & 63, wave = tid >> 6;
    const int m = lane & 15, quad = lane >> 4;
    const int rb = wave * 16;
    const int v = nodes_v[b];

    // q A-frags in regs (row-broadcast): qf[t][j] = q[t*32 + quad*8 + j]
    s16x8 qf[2];
#pragma unroll
    for (int t = 0; t < 2; ++t) {
        float4 qa = *(const float4*)(embed_i + v * 64 + t * 32 + quad * 8);
        float4 qb4 = *(const float4*)(embed_i + v * 64 + t * 32 + quad * 8 + 4);
        s16x8 r;
        r[0] = (short)f2b(qa.x);  r[1] = (short)f2b(qa.y);  r[2] = (short)f2b(qa.z);  r[3] = (short)f2b(qa.w);
        r[4] = (short)f2b(qb4.x); r[5] = (short)f2b(qb4.y); r[6] = (short)f2b(qb4.z); r[7] = (short)f2b(qb4.w);
        qf[t] = r;
    }
    if (tid < 64) qs[tid] = embed_i[v * 64 + tid];

    // wave-local gather: wave w stages rows [rb, rb+16); pt -> X[:,0:64], er -> X[:,64:128]
    {
        const int rsub = lane >> 4;   // 4 rows per iter
        const int c = lane & 15;      // 16B chunk (4 floats)
#pragma unroll
        for (int it = 0; it < 4; ++it) {
            int row = rb + it * 4 + rsub;
            float4 vu = make_float4(0.f, 0.f, 0.f, 0.f), vr = vu;
            if (row < L_) {
                int u = neigh_u[b * L_ + row];
                int r = neigh_r[b * L_ + row];
                vu = *(const float4*)(embed_u + u * 64 + c * 4);
                vr = *(const float4*)(embed_r + r * 64 + c * 4);
            }
            uint2 pu, pr;
            pu.x = pack2(vu.x, vu.y); pu.y = pack2(vu.z, vu.w);
            pr.x = pack2(vr.x, vr.y); pr.y = pack2(vr.z, vr.w);
            *(uint2*)(Xs + row * SX + c * 4) = pu;
            *(uint2*)(Xs + row * SX + 64 + c * 4) = pr;
        }
    }

    const bf16* w1t = wt + OFF_W1T;
    const bf16* w2t = wt + OFF_W2T;
    const bf16* w3t = wt + OFF_W3T;
    const bf16* wct = wt + OFF_WCAT;
    const bf16* a2t = wt + OFF_A2T;

    bf16* Xw = Xs + rb * SX;   // this wave's 16-row tile

    // gv1: X[:,0:128] -> h1 -> X[:,64:128]   (er dead after reads; same-wave WAR safe)
    layer<4, true>(Xw, SX, w1t, gv_b1, Xw + 64, SX, lane);
    // gv2: X[:,64:128] -> h2 -> X[:,0:64]
    layer<2, true>(Xw + 64, SX, w2t, gv_b2, Xw, SX, lane);

    // fused gv3 + att1': consume h2; fjt -> X[:,64:128], att1h -> X[:,0:64]
    {
        f32x4 accF[4] = {}, accA[4] = {};
#pragma unroll
        for (int kt = 0; kt < 2; ++kt) {
            s16x8 a = *(const s16x8*)(Xw + m * SX + kt * 32 + quad * 8);
#pragma unroll
            for (int nt = 0; nt < 4; ++nt) {
                s16x8 bF = *(const s16x8*)(w3t + (nt * 16 + m) * 64 + kt * 32 + quad * 8);
                s16x8 bA = *(const s16x8*)(wct + (nt * 16 + m) * 128 + kt * 32 + quad * 8);
                accF[nt] = __builtin_amdgcn_mfma_f32_16x16x32_bf16(a, bF, accF[nt], 0, 0, 0);
                accA[nt] = __builtin_amdgcn_mfma_f32_16x16x32_bf16(a, bA, accA[nt], 0, 0, 0);
            }
        }
#pragma unroll
        for (int kt = 2; kt < 4; ++kt) {
#pragma unroll
            for (int nt = 0; nt < 4; ++nt) {
                s16x8 bA = *(const s16x8*)(wct + (nt * 16 + m) * 128 + kt * 32 + quad * 8);
                accA[nt] = __builtin_amdgcn_mfma_f32_16x16x32_bf16(qf[kt - 2], bA, accA[nt], 0, 0, 0);
            }
        }
#pragma unroll
        for (int nt = 0; nt < 4; ++nt) {
            int c = nt * 16 + m;
            float b3v = gv_b3[c], b1v = bias1p[c];
#pragma unroll
            for (int r4 = 0; r4 < 4; ++r4) {
                int ro = (quad * 4 + r4) * SX;
                Xw[ro + 64 + c] = (bf16)(accF[nt][r4] + b3v);         // fjt (no relu)
                Xw[ro + c] = (bf16)fmaxf(accA[nt][r4] + b1v, 0.f);    // att1h
            }
        }
    }

    // att2 in regs + relu + dot(att_w3) + 16-lane reduce -> scores
    {
        f32x4 acc[4] = {};
#pragma unroll
        for (int kt = 0; kt < 2; ++kt) {
            s16x8 a = *(const s16x8*)(Xw + m * SX + kt * 32 + quad * 8);
#pragma unroll
            for (int nt = 0; nt < 4; ++nt) {
                s16x8 bb = *(const s16x8*)(a2t + (nt * 16 + m) * 64 + kt * 32 + quad * 8);
                acc[nt] = __builtin_amdgcn_mfma_f32_16x16x32_bf16(a, bb, acc[nt], 0, 0, 0);
            }
        }
        float sc[4] = {0.f, 0.f, 0.f, 0.f};
#pragma unroll
        for (int nt = 0; nt < 4; ++nt) {
            int c = nt * 16 + m;
            float b2v = att_b2[c], w3v = att_w3[c];
#pragma unroll
            for (int r4 = 0; r4 < 4; ++r4)
                sc[r4] += fmaxf(acc[nt][r4] + b2v, 0.f) * w3v;
        }
#pragma unroll
        for (int mask = 1; mask < 16; mask <<= 1)
#pragma unroll
            for (int r4 = 0; r4 < 4; ++r4) sc[r4] += __shfl_xor(sc[r4], mask);
        if (m == 0) {
#pragma unroll
            for (int r4 = 0; r4 < 4; ++r4) scs[rb + quad * 4 + r4] = sc[r4];
        }
    }
    __syncthreads();   // scs + fjt visible to all

    // softmax computed redundantly per-wave (regs only, no barrier, all waves stay busy)
    // att_b3 dropped: softmax is shift-invariant.
    {
        float s = (lane < L_) ? scs[lane] : -1e30f;
        float mx = s;
#pragma unroll
        for (int off = 32; off; off >>= 1) mx = fmaxf(mx, __shfl_xor(mx, off));
        float e = (lane < L_) ? __expf(s - mx) : 0.f;
        float sum = e;
#pragma unroll
        for (int off = 32; off; off >>= 1) sum += __shfl_xor(sum, off);
        float mu = e / sum;   // lane holds mu[lane]

        // zj partial: wave w reduces its own 16 fjt rows; mu[l] via shuffle broadcast
        float z = 0.f;
#pragma unroll
        for (int i = 0; i < 16; ++i) {
            int l = rb + i;
            z += (float)Xs[l * SX + 64 + lane] * __shfl(mu, l);
        }
        zp[wave * 64 + lane] = z;
    }
    __syncthreads();

    // combine tail on wave 0: out = relu(relu([zj|q] @ wr1 + b1) @ wr2 + b2)
    if (wave == 0) {
        float z = zp[lane] + zp[64 + lane] + zp[128 + lane] + zp[192 + lane];
        muS[lane] = z;   // share zj (same-wave in-order)

        float accz = wr1_b[lane];
        const bf16* r1 = wt + OFF_R1T + lane * 128;
#pragma unroll
        for (int k8 = 0; k8 < 8; ++k8) {
            b16x8 wv = *(const b16x8*)(r1 + k8 * 8);
#pragma unroll
            for (int j = 0; j < 8; ++j) accz = fmaf((float)wv[j], muS[k8 * 8 + j], accz);
        }
#pragma unroll
        for (int k8 = 0; k8 < 8; ++k8) {
            b16x8 wv = *(const b16x8*)(r1 + 64 + k8 * 8);
#pragma unroll
            for (int j = 0; j < 8; ++j) accz = fmaf((float)wv[j], qs[k8 * 8 + j], accz);
        }
        accz = fmaxf(accz, 0.f);
        scs[lane] = accz;   // share z2 (same-wave in-order)

        float acco = wr2_b[lane];
        const bf16* r2 = wt + OFF_R2T + lane * 64;
#pragma unroll
        for (int k8 = 0; k8 < 8; ++k8) {
            b16x8 wv = *(const b16x8*)(r2 + k8 * 8);
#pragma unroll
            for (int j = 0; j < 8; ++j) acco = fmaf((float)wv[j], scs[k8 * 8 + j], acco);
        }
        out[b * 64 + lane] = fmaxf(acco, 0.f);
    }
}

extern "C" void kernel_launch(void* const* d_in, const int* in_sizes, int n_in,
                              void* d_out, int out_size, void* d_ws, size_t ws_size,
                              hipStream_t stream)
{
    const int* nodes_v = (const int*)d_in[0];
    const int* neigh_u = (const int*)d_in[1];
    const int* neigh_r = (const int*)d_in[2];
    const float* embed_u = (const float*)d_in[3];
    const float* embed_i = (const float*)d_in[4];
    const float* embed_r = (const float*)d_in[5];
    const float* gv_w1  = (const float*)d_in[6];  const float* gv_b1 = (const float*)d_in[7];
    const float* gv_w2  = (const float*)d_in[8];  const float* gv_b2 = (const float*)d_in[9];
    const float* gv_w3  = (const float*)d_in[10]; const float* gv_b3 = (const float*)d_in[11];
    const float* att_w1 = (const float*)d_in[12]; const float* att_b1 = (const float*)d_in[13];
    const float* att_w2 = (const float*)d_in[14]; const float* att_b2 = (const float*)d_in[15];
    const float* att_w3 = (const float*)d_in[16]; const float* att_b3 = (const float*)d_in[17];
    const float* wr1_w  = (const float*)d_in[18]; const float* wr1_b = (const float*)d_in[19];
    const float* wr2_w  = (const float*)d_in[20]; const float* wr2_b = (const float*)d_in[21];
    (void)att_b3;

    bf16* wt      = (bf16*)d_ws;
    float* bias1p = (float*)((char*)d_ws + BIAS1P_BYTE);

    prep_weights<<<(WT_TOTAL + 64 + 255) / 256, 256, 0, stream>>>(
        gv_w1, gv_w2, gv_w3, att_w1, att_w2, wr1_w, wr2_w, gv_b3, att_b1, wt, bias1p);
    item_main<<<B_, 256, 0, stream>>>(nodes_v, neigh_u, neigh_r, embed_u, embed_i, embed_r,
                                      gv_b1, gv_b2, gv_b3, att_b2, att_w3,
                                      wr1_b, wr2_b, wt, bias1p, (float*)d_out);
}

// Round 7
// 189.398 us; speedup vs baseline: 1.4414x; 1.2780x over previous
//
#include <hip/hip_runtime.h>

typedef __bf16 bf16;
typedef short s16x8 __attribute__((ext_vector_type(8)));   // 8 bf16 bit-patterns for MFMA frags
typedef __bf16 b16x8 __attribute__((ext_vector_type(8)));  // 8 bf16 for scalar convert paths
typedef float f32x4 __attribute__((ext_vector_type(4)));

#define B_   4096
#define L_   50
#define NROW (B_ * L_)        // 204800 rows, 1600 blocks x 128 rows
#define SX   136              // X row stride (bf16): 128 + 8 pad

// ws layout. bf16 elems for wt:
#define OFF_W1T  0            // [64][128] gv_w1^T
#define OFF_W2T  8192         // [64][64]  gv_w2^T
#define OFF_W3T  12288        // [64][64]  gv_w3^T
#define OFF_WCA  16384        // [64][64]  (gv_w3 @ att_w1_top)^T
#define OFF_A2T  20480        // [64][64]  att_w2^T
#define OFF_R1T  24576        // [64][128] wr1^T
#define OFF_R2T  32768        // [64][64]  wr2^T
#define WT_TOTAL 36864
// byte offsets in ws:
#define BIAS1P_BYTE 73728     // float[64]   att_b1 + gv_b3 @ att_w1_top
#define C_BYTE      73984     // float[4096][64]  per-item att1 bias: q@A1_bot + bias1p
#define SC_BYTE     1122560   // float[204800]    attention scores
#define FJ_BYTE     1941760   // bf16 [204800][64] fjt

__device__ __forceinline__ unsigned short f2b(float f) {
    __bf16 h = (__bf16)f;
    return __builtin_bit_cast(unsigned short, h);
}
__device__ __forceinline__ unsigned pack2(float a, float b) {
    return (unsigned)f2b(a) | ((unsigned)f2b(b) << 16);
}
__device__ __forceinline__ int div50(int x) {  // exact for 0 <= x < 2^21
    return (int)(((unsigned long long)(unsigned)x * 2748779070ull) >> 37);
}

// Dual-tile layer: O_t = act(A_t @ W + bias) for two 16-row tiles sharing B-frags.
// HW-verified layouts: A[m=lane&15][k=quad*8+j]; B[k=quad*8+j][n=lane&15]; D col=lane&15,row=quad*4+reg.
template<int KT, bool RELU>
__device__ __forceinline__ void dual_layer(const bf16* A0, const bf16* A1,
                                           const bf16* Wp, const float* __restrict__ bias,
                                           bf16* O0, bf16* O1, int lane)
{
    const int m = lane & 15, quad = lane >> 4;
    f32x4 ac0[4] = {}, ac1[4] = {};
#pragma unroll
    for (int kt = 0; kt < KT; ++kt) {
        s16x8 a0 = *(const s16x8*)(A0 + m * SX + kt * 32 + quad * 8);
        s16x8 a1 = *(const s16x8*)(A1 + m * SX + kt * 32 + quad * 8);
#pragma unroll
        for (int nt = 0; nt < 4; ++nt) {
            s16x8 b = *(const s16x8*)(Wp + (nt * 16 + m) * (KT * 32) + kt * 32 + quad * 8);
            ac0[nt] = __builtin_amdgcn_mfma_f32_16x16x32_bf16(a0, b, ac0[nt], 0, 0, 0);
            ac1[nt] = __builtin_amdgcn_mfma_f32_16x16x32_bf16(a1, b, ac1[nt], 0, 0, 0);
        }
    }
#pragma unroll
    for (int nt = 0; nt < 4; ++nt) {
        int c = nt * 16 + m;
        float bv = bias[c];
#pragma unroll
        for (int r4 = 0; r4 < 4; ++r4) {
            float v0 = ac0[nt][r4] + bv, v1 = ac1[nt][r4] + bv;
            if (RELU) { v0 = fmaxf(v0, 0.f); v1 = fmaxf(v1, 0.f); }
            O0[(quad * 4 + r4) * SX + c] = (bf16)v0;
            O1[(quad * 4 + r4) * SX + c] = (bf16)v1;
        }
    }
}

// ---------------- prep 1: transposed bf16 weights + W3A1 fold + bias1' ----------------
extern "C" __global__ void prep_weights(const float* __restrict__ w1, const float* __restrict__ w2,
                                        const float* __restrict__ w3, const float* __restrict__ a1,
                                        const float* __restrict__ a2, const float* __restrict__ r1,
                                        const float* __restrict__ r2, const float* __restrict__ gb3,
                                        const float* __restrict__ ab1,
                                        bf16* __restrict__ wt, float* __restrict__ bias1p)
{
    int i = blockIdx.x * blockDim.x + threadIdx.x;
    if (i >= WT_TOTAL + 64) return;
    if (i >= WT_TOTAL) {                       // bias1'[n] = ab1[n] + sum_t gb3[t]*a1[t][n]
        int n = i - WT_TOTAL;
        float s0 = ab1[n], s1 = 0.f, s2 = 0.f, s3 = 0.f;
#pragma unroll
        for (int t = 0; t < 64; t += 4) {
            s0 = fmaf(gb3[t],     a1[t * 64 + n],       s0);
            s1 = fmaf(gb3[t + 1], a1[(t + 1) * 64 + n], s1);
            s2 = fmaf(gb3[t + 2], a1[(t + 2) * 64 + n], s2);
            s3 = fmaf(gb3[t + 3], a1[(t + 3) * 64 + n], s3);
        }
        bias1p[n] = (s0 + s1) + (s2 + s3);
        return;
    }
    float val;
    if (i < OFF_W2T)      { int li = i;            int n = li >> 7, k = li & 127; val = w1[k * 64 + n]; }
    else if (i < OFF_W3T) { int li = i - OFF_W2T;  int n = li >> 6, k = li & 63;  val = w2[k * 64 + n]; }
    else if (i < OFF_WCA) { int li = i - OFF_W3T;  int n = li >> 6, k = li & 63;  val = w3[k * 64 + n]; }
    else if (i < OFF_A2T) {                        // wca[n][k] = (W3 @ A1_top)[k][n]
        int li = i - OFF_WCA; int n = li >> 6, k = li & 63;
        float s0 = 0.f, s1 = 0.f, s2 = 0.f, s3 = 0.f;
#pragma unroll
        for (int t = 0; t < 64; t += 4) {
            float4 w = *(const float4*)(w3 + k * 64 + t);
            s0 = fmaf(w.x, a1[t * 64 + n],       s0);
            s1 = fmaf(w.y, a1[(t + 1) * 64 + n], s1);
            s2 = fmaf(w.z, a1[(t + 2) * 64 + n], s2);
            s3 = fmaf(w.w, a1[(t + 3) * 64 + n], s3);
        }
        val = (s0 + s1) + (s2 + s3);
    }
    else if (i < OFF_R1T) { int li = i - OFF_A2T;  int n = li >> 6, k = li & 63;  val = a2[k * 64 + n]; }
    else if (i < OFF_R2T) { int li = i - OFF_R1T;  int n = li >> 7, k = li & 127; val = r1[k * 64 + n]; }
    else                  { int li = i - OFF_R2T;  int n = li >> 6, k = li & 63;  val = r2[k * 64 + n]; }
    wt[i] = (bf16)val;
}

// ---------------- prep 2: per-item att1 bias c[b][n] = bias1p[n] + q_b @ A1_bot ----------------
extern "C" __global__ void __launch_bounds__(256, 4)
prep_citem(const int* __restrict__ nodes_v, const float* __restrict__ embed_i,
           const float* __restrict__ a1, const float* __restrict__ bias1p,
           float* __restrict__ cft)
{
    int gid = blockIdx.x * blockDim.x + threadIdx.x;   // 4096*64
    int b = gid >> 6, n = gid & 63;
    int v = nodes_v[b];
    const float* q = embed_i + v * 64;
    float s0 = bias1p[n], s1 = 0.f, s2 = 0.f, s3 = 0.f;
#pragma unroll
    for (int k = 0; k < 64; k += 4) {
        s0 = fmaf(q[k],     a1[(64 + k) * 64 + n],     s0);
        s1 = fmaf(q[k + 1], a1[(64 + k + 1) * 64 + n], s1);
        s2 = fmaf(q[k + 2], a1[(64 + k + 2) * 64 + n], s2);
        s3 = fmaf(q[k + 3], a1[(64 + k + 3) * 64 + n], s3);
    }
    cft[gid] = (s0 + s1) + (s2 + s3);
}

// ---------------- phase A: dense 5-layer MFMA over all 204800 rows ----------------
// 128 rows/block, 4 waves x two 16-row tiles. K=64 weights in LDS; w1t streamed from L2.
extern "C" __global__ void __launch_bounds__(256, 2)
dense_fwd(const int* __restrict__ neigh_u, const int* __restrict__ neigh_r,
          const float* __restrict__ embed_u, const float* __restrict__ embed_r,
          const float* __restrict__ gv_b1, const float* __restrict__ gv_b2,
          const float* __restrict__ gv_b3,
          const float* __restrict__ att_b2, const float* __restrict__ att_w3,
          const bf16* __restrict__ wt, const float* __restrict__ cft,
          bf16* __restrict__ fj, float* __restrict__ scg)
{
    __shared__ __align__(16) bf16 Xs[128 * SX];     // 34816 B
    __shared__ __align__(16) bf16 Ws[16384];        // 32768 B: w2|w3|wca|a2 (K=64 each)
    __shared__ float csS[4 * 64];                   // per-item att1 bias for items b0..b0+3

    const int tid = threadIdx.x;
    const int lane = tid & 63, wave = tid >> 6;
    const int m = lane & 15, quad = lane >> 4;
    const int r0 = blockIdx.x * 128;
    const int b0 = div50(r0);

    // stage K=64 weights (wt elems 8192..24576) -> LDS, coalesced 16B chunks
    {
        const uint4* src = (const uint4*)(wt + OFF_W2T);
        uint4* dst = (uint4*)Ws;
#pragma unroll
        for (int it = 0; it < 8; ++it) dst[tid + it * 256] = src[tid + it * 256];
    }
    // stage per-item att1 bias rows (<=4 distinct items per 128 rows)
    {
        int i = tid >> 6, n = tid & 63;
        int bi = b0 + i; if (bi > B_ - 1) bi = B_ - 1;
        csS[tid] = cft[bi * 64 + n];
    }

    // wave-local gather of 32 rows: pt -> X[:,0:64], er -> X[:,64:128]
    const int rw0 = wave * 32;
    {
        const int rsub = lane >> 4;   // 4 rows per iter
        const int c = lane & 15;      // 16B chunk
#pragma unroll
        for (int it = 0; it < 8; ++it) {
            int rloc = rw0 + it * 4 + rsub;
            int rg = r0 + rloc;
            int u = neigh_u[rg];
            int r = neigh_r[rg];
            float4 vu = *(const float4*)(embed_u + u * 64 + c * 4);
            float4 vr = *(const float4*)(embed_r + r * 64 + c * 4);
            uint2 pu, pr;
            pu.x = pack2(vu.x, vu.y); pu.y = pack2(vu.z, vu.w);
            pr.x = pack2(vr.x, vr.y); pr.y = pack2(vr.z, vr.w);
            *(uint2*)(Xs + rloc * SX + c * 4) = pu;
            *(uint2*)(Xs + rloc * SX + 64 + c * 4) = pr;
        }
    }

    bf16* X0 = Xs + rw0 * SX;          // tile 0 rows
    bf16* X1 = Xs + (rw0 + 16) * SX;   // tile 1 rows

    // gv1: X[:,0:128] -> h1 -> X[:,64:128]; B-frags streamed from global w1t (shared by both tiles)
    dual_layer<4, true>(X0, X1, wt + OFF_W1T, gv_b1, X0 + 64, X1 + 64, lane);

    __syncthreads();   // Ws + csS ready (staged by all threads)

    // gv2: h1 -> h2 -> X[:,0:64]; weights from LDS
    dual_layer<2, true>(X0 + 64, X1 + 64, Ws, gv_b2, X0, X1, lane);

    // fused gv3 + att1': consume h2; fjt -> X[:,64:128], att1h -> X[:,0:64]
    {
        const bf16* w3s = Ws + 4096;
        const bf16* wcs = Ws + 8192;
        f32x4 aF0[4] = {}, aF1[4] = {}, aA0[4] = {}, aA1[4] = {};
#pragma unroll
        for (int kt = 0; kt < 2; ++kt) {
            s16x8 a0 = *(const s16x8*)(X0 + m * SX + kt * 32 + quad * 8);
            s16x8 a1 = *(const s16x8*)(X1 + m * SX + kt * 32 + quad * 8);
#pragma unroll
            for (int nt = 0; nt < 4; ++nt) {
                s16x8 bF = *(const s16x8*)(w3s + (nt * 16 + m) * 64 + kt * 32 + quad * 8);
                s16x8 bA = *(const s16x8*)(wcs + (nt * 16 + m) * 64 + kt * 32 + quad * 8);
                aF0[nt] = __builtin_amdgcn_mfma_f32_16x16x32_bf16(a0, bF, aF0[nt], 0, 0, 0);
                aF1[nt] = __builtin_amdgcn_mfma_f32_16x16x32_bf16(a1, bF, aF1[nt], 0, 0, 0);
                aA0[nt] = __builtin_amdgcn_mfma_f32_16x16x32_bf16(a0, bA, aA0[nt], 0, 0, 0);
                aA1[nt] = __builtin_amdgcn_mfma_f32_16x16x32_bf16(a1, bA, aA1[nt], 0, 0, 0);
            }
        }
#pragma unroll
        for (int nt = 0; nt < 4; ++nt) {
            int c = nt * 16 + m;
            float b3v = gv_b3[c];
#pragma unroll
            for (int r4 = 0; r4 < 4; ++r4) {
                int rl0 = rw0 + quad * 4 + r4, rl1 = rl0 + 16;
                int i0 = div50(r0 + rl0) - b0, i1 = div50(r0 + rl1) - b0;
                Xs[rl0 * SX + 64 + c] = (bf16)(aF0[nt][r4] + b3v);
                Xs[rl1 * SX + 64 + c] = (bf16)(aF1[nt][r4] + b3v);
                Xs[rl0 * SX + c] = (bf16)fmaxf(aA0[nt][r4] + csS[i0 * 64 + c], 0.f);
                Xs[rl1 * SX + c] = (bf16)fmaxf(aA1[nt][r4] + csS[i1 * 64 + c], 0.f);
            }
        }
    }

    // att2 in regs + relu + dot(att_w3) + 16-lane reduce -> scores (global)
    {
        const bf16* a2s = Ws + 12288;
        f32x4 ac0[4] = {}, ac1[4] = {};
#pragma unroll
        for (int kt = 0; kt < 2; ++kt) {
            s16x8 a0 = *(const s16x8*)(X0 + m * SX + kt * 32 + quad * 8);
            s16x8 a1 = *(const s16x8*)(X1 + m * SX + kt * 32 + quad * 8);
#pragma unroll
            for (int nt = 0; nt < 4; ++nt) {
                s16x8 b = *(const s16x8*)(a2s + (nt * 16 + m) * 64 + kt * 32 + quad * 8);
                ac0[nt] = __builtin_amdgcn_mfma_f32_16x16x32_bf16(a0, b, ac0[nt], 0, 0, 0);
                ac1[nt] = __builtin_amdgcn_mfma_f32_16x16x32_bf16(a1, b, ac1[nt], 0, 0, 0);
            }
        }
        float s0[4] = {0.f, 0.f, 0.f, 0.f}, s1[4] = {0.f, 0.f, 0.f, 0.f};
#pragma unroll
        for (int nt = 0; nt < 4; ++nt) {
            int c = nt * 16 + m;
            float b2v = att_b2[c], w3v = att_w3[c];
#pragma unroll
            for (int r4 = 0; r4 < 4; ++r4) {
                s0[r4] += fmaxf(ac0[nt][r4] + b2v, 0.f) * w3v;
                s1[r4] += fmaxf(ac1[nt][r4] + b2v, 0.f) * w3v;
            }
        }
#pragma unroll
        for (int mask = 1; mask < 16; mask <<= 1)
#pragma unroll
            for (int r4 = 0; r4 < 4; ++r4) {
                s0[r4] += __shfl_xor(s0[r4], mask);
                s1[r4] += __shfl_xor(s1[r4], mask);
            }
        if (m == 0) {
#pragma unroll
            for (int r4 = 0; r4 < 4; ++r4) {
                scg[r0 + rw0 + quad * 4 + r4] = s0[r4];
                scg[r0 + rw0 + 16 + quad * 4 + r4] = s1[r4];
            }
        }
    }

    // fjt (X[:,64:128]) -> global, coalesced 16B chunks (wave-local rows)
    {
        const int rsub = lane >> 3;   // 8 rows per iter
        const int ch = lane & 7;
#pragma unroll
        for (int it = 0; it < 4; ++it) {
            int rloc = rw0 + it * 8 + rsub;
            *(uint4*)(fj + (r0 + rloc) * 64 + ch * 8) =
                *(const uint4*)(Xs + rloc * SX + 64 + ch * 8);
        }
    }
}

// ---------------- phase B: per-item softmax + zj + combine ----------------
extern "C" __global__ void __launch_bounds__(256, 4)
aggregate(const int* __restrict__ nodes_v, const float* __restrict__ embed_i,
          const float* __restrict__ scg, const bf16* __restrict__ fj,
          const float* __restrict__ wr1_b, const float* __restrict__ wr2_b,
          const bf16* __restrict__ wt, float* __restrict__ out)
{
    __shared__ float qsh[4][64];
    __shared__ float zsh[4][64];
    __shared__ float z2sh[4][64];

    const int tid = threadIdx.x;
    const int lane = tid & 63, wave = tid >> 6;
    const int b = blockIdx.x * 4 + wave;
    const int d = lane;

    // softmax over scores (lane = neighbor index)
    float s = (lane < L_) ? scg[b * L_ + lane] : -1e30f;
    float mx = s;
#pragma unroll
    for (int off = 32; off; off >>= 1) mx = fmaxf(mx, __shfl_xor(mx, off));
    float e = (lane < L_) ? __expf(s - mx) : 0.f;
    float sum = e;
#pragma unroll
    for (int off = 32; off; off >>= 1) sum += __shfl_xor(sum, off);
    float mu = e / sum;

    // zj[d] = sum_l fjt[l][d] * mu[l]
    const bf16* fb = fj + b * L_ * 64;
    float z = 0.f;
#pragma unroll
    for (int l = 0; l < L_; ++l)
        z += (float)fb[l * 64 + d] * __shfl(mu, l);
    zsh[wave][d] = z;
    int v = nodes_v[b];
    qsh[wave][d] = embed_i[v * 64 + d];
    // same-wave LDS RAW (DS pipe in-order) -> no barrier

    // z2 = relu([zj|q] @ wr1 + b1)
    float accz = wr1_b[d];
    const bf16* r1 = wt + OFF_R1T + d * 128;
#pragma unroll
    for (int k8 = 0; k8 < 8; ++k8) {
        b16x8 wv = *(const b16x8*)(r1 + k8 * 8);
#pragma unroll
        for (int j = 0; j < 8; ++j) accz = fmaf((float)wv[j], zsh[wave][k8 * 8 + j], accz);
    }
#pragma unroll
    for (int k8 = 0; k8 < 8; ++k8) {
        b16x8 wv = *(const b16x8*)(r1 + 64 + k8 * 8);
#pragma unroll
        for (int j = 0; j < 8; ++j) accz = fmaf((float)wv[j], qsh[wave][k8 * 8 + j], accz);
    }
    z2sh[wave][d] = fmaxf(accz, 0.f);

    // out = relu(z2 @ wr2 + b2)
    float acco = wr2_b[d];
    const bf16* r2 = wt + OFF_R2T + d * 64;
#pragma unroll
    for (int k8 = 0; k8 < 8; ++k8) {
        b16x8 wv = *(const b16x8*)(r2 + k8 * 8);
#pragma unroll
        for (int j = 0; j < 8; ++j) acco = fmaf((float)wv[j], z2sh[wave][k8 * 8 + j], acco);
    }
    out[b * 64 + d] = fmaxf(acco, 0.f);
}

extern "C" void kernel_launch(void* const* d_in, const int* in_sizes, int n_in,
                              void* d_out, int out_size, void* d_ws, size_t ws_size,
                              hipStream_t stream)
{
    const int* nodes_v = (const int*)d_in[0];
    const int* neigh_u = (const int*)d_in[1];
    const int* neigh_r = (const int*)d_in[2];
    const float* embed_u = (const float*)d_in[3];
    const float* embed_i = (const float*)d_in[4];
    const float* embed_r = (const float*)d_in[5];
    const float* gv_w1  = (const float*)d_in[6];  const float* gv_b1 = (const float*)d_in[7];
    const float* gv_w2  = (const float*)d_in[8];  const float* gv_b2 = (const float*)d_in[9];
    const float* gv_w3  = (const float*)d_in[10]; const float* gv_b3 = (const float*)d_in[11];
    const float* att_w1 = (const float*)d_in[12]; const float* att_b1 = (const float*)d_in[13];
    const float* att_w2 = (const float*)d_in[14]; const float* att_b2 = (const float*)d_in[15];
    const float* att_w3 = (const float*)d_in[16]; const float* att_b3 = (const float*)d_in[17];
    const float* wr1_w  = (const float*)d_in[18]; const float* wr1_b = (const float*)d_in[19];
    const float* wr2_w  = (const float*)d_in[20]; const float* wr2_b = (const float*)d_in[21];
    (void)att_b3;  // softmax shift-invariance

    bf16*  wt     = (bf16*)d_ws;
    float* bias1p = (float*)((char*)d_ws + BIAS1P_BYTE);
    float* cft    = (float*)((char*)d_ws + C_BYTE);
    float* scg    = (float*)((char*)d_ws + SC_BYTE);
    bf16*  fjp    = (bf16*)((char*)d_ws + FJ_BYTE);

    prep_weights<<<(WT_TOTAL + 64 + 255) / 256, 256, 0, stream>>>(
        gv_w1, gv_w2, gv_w3, att_w1, att_w2, wr1_w, wr2_w, gv_b3, att_b1, wt, bias1p);
    prep_citem<<<(B_ * 64) / 256, 256, 0, stream>>>(nodes_v, embed_i, att_w1, bias1p, cft);
    dense_fwd<<<NROW / 128, 256, 0, stream>>>(neigh_u, neigh_r, embed_u, embed_r,
                                              gv_b1, gv_b2, gv_b3, att_b2, att_w3,
                                              wt, cft, fjp, scg);
    aggregate<<<B_ / 4, 256, 0, stream>>>(nodes_v, embed_i, scg, fjp,
                                          wr1_b, wr2_b, wt, (float*)d_out);
}

// Round 8
// 172.156 us; speedup vs baseline: 1.5857x; 1.1002x over previous
//
#include <hip/hip_runtime.h>

typedef __bf16 bf16;
typedef short s16x8 __attribute__((ext_vector_type(8)));   // 8 bf16 bit-patterns for MFMA frags
typedef __bf16 b16x8 __attribute__((ext_vector_type(8)));  // 8 bf16 for scalar convert paths
typedef float f32x4 __attribute__((ext_vector_type(4)));

#define B_   4096
#define L_   50
#define NROW (B_ * L_)        // 204800 rows, 1600 blocks x 128 rows
#define SX   136              // X row stride (bf16): 128 + 8 pad

// ws layout, bf16 elems. Frag-major matrices: frag f = kt*4+nt is a contiguous
// 512-elem (1 KB) block; elem index = f*512 + lane*8 + j, holding W[k=kt*32+(lane>>4)*8+j][n=nt*16+(lane&15)].
#define OFF_W1F  0            // gv_w1  frag-major, K=128 (16 frags)
#define OFF_W2F  8192         // gv_w2  frag-major, K=64  (8 frags)
#define OFF_W3F  12288        // gv_w3  frag-major
#define OFF_WCF  16384        // (gv_w3 @ att_w1_top) frag-major
#define OFF_A2F  20480        // att_w2 frag-major
#define OFF_R1T  24576        // [64][128] wr1^T row-major (aggregate's per-lane dots)
#define OFF_R2T  32768        // [64][64]  wr2^T row-major
#define WT_TOTAL 36864
// byte offsets in ws:
#define BIAS1P_BYTE 73728     // float[64]   att_b1 + gv_b3 @ att_w1_top
#define C_BYTE      73984     // float[4096][64]  per-item att1 bias: q@A1_bot + bias1p
#define SC_BYTE     1122560   // float[204800]    attention scores
#define FJ_BYTE     1941760   // bf16 [204800][64] fjt

__device__ __forceinline__ unsigned short f2b(float f) {
    __bf16 h = (__bf16)f;
    return __builtin_bit_cast(unsigned short, h);
}
__device__ __forceinline__ unsigned pack2(float a, float b) {
    return (unsigned)f2b(a) | ((unsigned)f2b(b) << 16);
}
__device__ __forceinline__ int div50(int x) {  // exact for 0 <= x < 2^21
    return (int)(((unsigned long long)(unsigned)x * 2748779070ull) >> 37);
}

// Dual-tile layer: O_t = act(A_t @ W + bias), two 16-row tiles share B-frags.
// B-frags from frag-major global weights: 1 KB coalesced load per (kt,nt), L1-hot.
// HW-verified layouts: A[m=lane&15][k=quad*8+j]; D col=lane&15, row=quad*4+reg.
template<int KT, bool RELU>
__device__ __forceinline__ void dual_layer(const bf16* A0, const bf16* A1,
                                           const bf16* __restrict__ Wf,
                                           const float* __restrict__ bias,
                                           bf16* O0, bf16* O1, int lane)
{
    const int m = lane & 15, quad = lane >> 4;
    f32x4 ac0[4] = {}, ac1[4] = {};
#pragma unroll
    for (int kt = 0; kt < KT; ++kt) {
        s16x8 a0 = *(const s16x8*)(A0 + m * SX + kt * 32 + quad * 8);
        s16x8 a1 = *(const s16x8*)(A1 + m * SX + kt * 32 + quad * 8);
#pragma unroll
        for (int nt = 0; nt < 4; ++nt) {
            s16x8 b = *(const s16x8*)(Wf + (kt * 4 + nt) * 512 + lane * 8);
            ac0[nt] = __builtin_amdgcn_mfma_f32_16x16x32_bf16(a0, b, ac0[nt], 0, 0, 0);
            ac1[nt] = __builtin_amdgcn_mfma_f32_16x16x32_bf16(a1, b, ac1[nt], 0, 0, 0);
        }
    }
#pragma unroll
    for (int nt = 0; nt < 4; ++nt) {
        int c = nt * 16 + m;
        float bv = bias[c];
#pragma unroll
        for (int r4 = 0; r4 < 4; ++r4) {
            float v0 = ac0[nt][r4] + bv, v1 = ac1[nt][r4] + bv;
            if (RELU) { v0 = fmaxf(v0, 0.f); v1 = fmaxf(v1, 0.f); }
            O0[(quad * 4 + r4) * SX + c] = (bf16)v0;
            O1[(quad * 4 + r4) * SX + c] = (bf16)v1;
        }
    }
}

// ---------------- prep 1: frag-major bf16 weights + W3A1 fold + bias1' ----------------
extern "C" __global__ void prep_weights(const float* __restrict__ w1, const float* __restrict__ w2,
                                        const float* __restrict__ w3, const float* __restrict__ a1,
                                        const float* __restrict__ a2, const float* __restrict__ r1,
                                        const float* __restrict__ r2, const float* __restrict__ gb3,
                                        const float* __restrict__ ab1,
                                        bf16* __restrict__ wt, float* __restrict__ bias1p)
{
    int i = blockIdx.x * blockDim.x + threadIdx.x;
    if (i >= WT_TOTAL + 64) return;
    if (i >= WT_TOTAL) {                       // bias1'[n] = ab1[n] + sum_t gb3[t]*a1[t][n]
        int n = i - WT_TOTAL;
        float s0 = ab1[n], s1 = 0.f, s2 = 0.f, s3 = 0.f;
#pragma unroll
        for (int t = 0; t < 64; t += 4) {
            s0 = fmaf(gb3[t],     a1[t * 64 + n],       s0);
            s1 = fmaf(gb3[t + 1], a1[(t + 1) * 64 + n], s1);
            s2 = fmaf(gb3[t + 2], a1[(t + 2) * 64 + n], s2);
            s3 = fmaf(gb3[t + 3], a1[(t + 3) * 64 + n], s3);
        }
        bias1p[n] = (s0 + s1) + (s2 + s3);
        return;
    }
    float val;
    if (i < OFF_R1T) {
        // frag-major regions: local = f*512 + lane*8 + j
        int off, kind;   // kind: 0=w1,1=w2,2=w3,3=wca,4=a2
        if      (i < OFF_W2F) { off = OFF_W1F; kind = 0; }
        else if (i < OFF_W3F) { off = OFF_W2F; kind = 1; }
        else if (i < OFF_WCF) { off = OFF_W3F; kind = 2; }
        else if (i < OFF_A2F) { off = OFF_WCF; kind = 3; }
        else                  { off = OFF_A2F; kind = 4; }
        int local = i - off;
        int f = local >> 9, lane = (local >> 3) & 63, j = local & 7;
        int kt = f >> 2, nt = f & 3, quad = lane >> 4, m = lane & 15;
        int k = kt * 32 + quad * 8 + j;
        int n = nt * 16 + m;
        if (kind == 0)      val = w1[k * 64 + n];
        else if (kind == 1) val = w2[k * 64 + n];
        else if (kind == 2) val = w3[k * 64 + n];
        else if (kind == 4) val = a2[k * 64 + n];
        else {                                  // wca[k][n] = (W3 @ A1_top)[k][n]
            float s0 = 0.f, s1 = 0.f, s2 = 0.f, s3 = 0.f;
#pragma unroll
            for (int t = 0; t < 64; t += 4) {
                float4 w = *(const float4*)(w3 + k * 64 + t);
                s0 = fmaf(w.x, a1[t * 64 + n],       s0);
                s1 = fmaf(w.y, a1[(t + 1) * 64 + n], s1);
                s2 = fmaf(w.z, a1[(t + 2) * 64 + n], s2);
                s3 = fmaf(w.w, a1[(t + 3) * 64 + n], s3);
            }
            val = (s0 + s1) + (s2 + s3);
        }
    }
    else if (i < OFF_R2T) { int li = i - OFF_R1T; int n = li >> 7, k = li & 127; val = r1[k * 64 + n]; }
    else                  { int li = i - OFF_R2T; int n = li >> 6, k = li & 63;  val = r2[k * 64 + n]; }
    wt[i] = (bf16)val;
}

// ---------------- prep 2: per-item att1 bias c[b][n] = bias1p[n] + q_b @ A1_bot ----------------
extern "C" __global__ void __launch_bounds__(256, 4)
prep_citem(const int* __restrict__ nodes_v, const float* __restrict__ embed_i,
           const float* __restrict__ a1, const float* __restrict__ bias1p,
           float* __restrict__ cft)
{
    int gid = blockIdx.x * blockDim.x + threadIdx.x;   // 4096*64
    int b = gid >> 6, n = gid & 63;
    int v = nodes_v[b];
    const float* q = embed_i + v * 64;
    float s0 = bias1p[n], s1 = 0.f, s2 = 0.f, s3 = 0.f;
#pragma unroll
    for (int k = 0; k < 64; k += 4) {
        s0 = fmaf(q[k],     a1[(64 + k) * 64 + n],     s0);
        s1 = fmaf(q[k + 1], a1[(64 + k + 1) * 64 + n], s1);
        s2 = fmaf(q[k + 2], a1[(64 + k + 2) * 64 + n], s2);
        s3 = fmaf(q[k + 3], a1[(64 + k + 3) * 64 + n], s3);
    }
    cft[gid] = (s0 + s1) + (s2 + s3);
}

// ---------------- phase A: dense 5-layer MFMA over all 204800 rows ----------------
// 128 rows/block, 4 waves x two 16-row tiles. B-frags: coalesced frag-major global (L1-hot).
// LDS = Xs only (35.8 KB) -> 4 blocks/CU; VGPR 88 @ (256,2) -> 4 waves/SIMD. Balanced at 4.
extern "C" __global__ void __launch_bounds__(256, 2)
dense_fwd(const int* __restrict__ neigh_u, const int* __restrict__ neigh_r,
          const float* __restrict__ embed_u, const float* __restrict__ embed_r,
          const float* __restrict__ gv_b1, const float* __restrict__ gv_b2,
          const float* __restrict__ gv_b3,
          const float* __restrict__ att_b2, const float* __restrict__ att_w3,
          const bf16* __restrict__ wt, const float* __restrict__ cft,
          bf16* __restrict__ fj, float* __restrict__ scg)
{
    __shared__ __align__(16) bf16 Xs[128 * SX];     // 34816 B
    __shared__ float csS[4 * 64];                   // per-item att1 bias, items b0..b0+3

    const int tid = threadIdx.x;
    const int lane = tid & 63, wave = tid >> 6;
    const int m = lane & 15, quad = lane >> 4;
    const int r0 = blockIdx.x * 128;
    const int b0 = div50(r0);

    // stage per-item att1 bias rows (<=4 distinct items per 128 rows)
    {
        int i = tid >> 6, n = tid & 63;
        int bi = b0 + i; if (bi > B_ - 1) bi = B_ - 1;
        csS[tid] = cft[bi * 64 + n];
    }

    // wave-local gather of 32 rows: pt -> X[:,0:64], er -> X[:,64:128]
    const int rw0 = wave * 32;
    {
        const int rsub = lane >> 4;   // 4 rows per iter
        const int c = lane & 15;      // 16B chunk
#pragma unroll
        for (int it = 0; it < 8; ++it) {
            int rloc = rw0 + it * 4 + rsub;
            int rg = r0 + rloc;
            int u = neigh_u[rg];
            int r = neigh_r[rg];
            float4 vu = *(const float4*)(embed_u + u * 64 + c * 4);
            float4 vr = *(const float4*)(embed_r + r * 64 + c * 4);
            uint2 pu, pr;
            pu.x = pack2(vu.x, vu.y); pu.y = pack2(vu.z, vu.w);
            pr.x = pack2(vr.x, vr.y); pr.y = pack2(vr.z, vr.w);
            *(uint2*)(Xs + rloc * SX + c * 4) = pu;
            *(uint2*)(Xs + rloc * SX + 64 + c * 4) = pr;
        }
    }

    bf16* X0 = Xs + rw0 * SX;          // tile 0 rows
    bf16* X1 = Xs + (rw0 + 16) * SX;   // tile 1 rows

    // gv1: X[:,0:128] -> h1 -> X[:,64:128]  (er dead after reads; same-wave WAR safe)
    dual_layer<4, true>(X0, X1, wt + OFF_W1F, gv_b1, X0 + 64, X1 + 64, lane);

    __syncthreads();   // csS visible to all (only cross-wave dependency)

    // gv2: h1 -> h2 -> X[:,0:64]
    dual_layer<2, true>(X0 + 64, X1 + 64, wt + OFF_W2F, gv_b2, X0, X1, lane);

    // fused gv3 + att1': consume h2; fjt -> X[:,64:128], att1h -> X[:,0:64]
    {
        const bf16* w3f = wt + OFF_W3F;
        const bf16* wcf = wt + OFF_WCF;
        f32x4 aF0[4] = {}, aF1[4] = {}, aA0[4] = {}, aA1[4] = {};
#pragma unroll
        for (int kt = 0; kt < 2; ++kt) {
            s16x8 a0 = *(const s16x8*)(X0 + m * SX + kt * 32 + quad * 8);
            s16x8 a1 = *(const s16x8*)(X1 + m * SX + kt * 32 + quad * 8);
#pragma unroll
            for (int nt = 0; nt < 4; ++nt) {
                s16x8 bF = *(const s16x8*)(w3f + (kt * 4 + nt) * 512 + lane * 8);
                s16x8 bA = *(const s16x8*)(wcf + (kt * 4 + nt) * 512 + lane * 8);
                aF0[nt] = __builtin_amdgcn_mfma_f32_16x16x32_bf16(a0, bF, aF0[nt], 0, 0, 0);
                aF1[nt] = __builtin_amdgcn_mfma_f32_16x16x32_bf16(a1, bF, aF1[nt], 0, 0, 0);
                aA0[nt] = __builtin_amdgcn_mfma_f32_16x16x32_bf16(a0, bA, aA0[nt], 0, 0, 0);
                aA1[nt] = __builtin_amdgcn_mfma_f32_16x16x32_bf16(a1, bA, aA1[nt], 0, 0, 0);
            }
        }
#pragma unroll
        for (int nt = 0; nt < 4; ++nt) {
            int c = nt * 16 + m;
            float b3v = gv_b3[c];
#pragma unroll
            for (int r4 = 0; r4 < 4; ++r4) {
                int rl0 = rw0 + quad * 4 + r4, rl1 = rl0 + 16;
                int i0 = div50(r0 + rl0) - b0, i1 = div50(r0 + rl1) - b0;
                Xs[rl0 * SX + 64 + c] = (bf16)(aF0[nt][r4] + b3v);
                Xs[rl1 * SX + 64 + c] = (bf16)(aF1[nt][r4] + b3v);
                Xs[rl0 * SX + c] = (bf16)fmaxf(aA0[nt][r4] + csS[i0 * 64 + c], 0.f);
                Xs[rl1 * SX + c] = (bf16)fmaxf(aA1[nt][r4] + csS[i1 * 64 + c], 0.f);
            }
        }
    }

    // att2 in regs + relu + dot(att_w3) + 16-lane reduce -> scores (global)
    {
        const bf16* a2f = wt + OFF_A2F;
        f32x4 ac0[4] = {}, ac1[4] = {};
#pragma unroll
        for (int kt = 0; kt < 2; ++kt) {
            s16x8 a0 = *(const s16x8*)(X0 + m * SX + kt * 32 + quad * 8);
            s16x8 a1 = *(const s16x8*)(X1 + m * SX + kt * 32 + quad * 8);
#pragma unroll
            for (int nt = 0; nt < 4; ++nt) {
                s16x8 b = *(const s16x8*)(a2f + (kt * 4 + nt) * 512 + lane * 8);
                ac0[nt] = __builtin_amdgcn_mfma_f32_16x16x32_bf16(a0, b, ac0[nt], 0, 0, 0);
                ac1[nt] = __builtin_amdgcn_mfma_f32_16x16x32_bf16(a1, b, ac1[nt], 0, 0, 0);
            }
        }
        float s0[4] = {0.f, 0.f, 0.f, 0.f}, s1[4] = {0.f, 0.f, 0.f, 0.f};
#pragma unroll
        for (int nt = 0; nt < 4; ++nt) {
            int c = nt * 16 + m;
            float b2v = att_b2[c], w3v = att_w3[c];
#pragma unroll
            for (int r4 = 0; r4 < 4; ++r4) {
                s0[r4] += fmaxf(ac0[nt][r4] + b2v, 0.f) * w3v;
                s1[r4] += fmaxf(ac1[nt][r4] + b2v, 0.f) * w3v;
            }
        }
#pragma unroll
        for (int mask = 1; mask < 16; mask <<= 1)
#pragma unroll
            for (int r4 = 0; r4 < 4; ++r4) {
                s0[r4] += __shfl_xor(s0[r4], mask);
                s1[r4] += __shfl_xor(s1[r4], mask);
            }
        if (m == 0) {
#pragma unroll
            for (int r4 = 0; r4 < 4; ++r4) {
                scg[r0 + rw0 + quad * 4 + r4] = s0[r4];
                scg[r0 + rw0 + 16 + quad * 4 + r4] = s1[r4];
            }
        }
    }

    // fjt (X[:,64:128]) -> global, coalesced 16B chunks (wave-local rows)
    {
        const int rsub = lane >> 3;   // 8 rows per iter
        const int ch = lane & 7;
#pragma unroll
        for (int it = 0; it < 4; ++it) {
            int rloc = rw0 + it * 8 + rsub;
            *(uint4*)(fj + (r0 + rloc) * 64 + ch * 8) =
                *(const uint4*)(Xs + rloc * SX + 64 + ch * 8);
        }
    }
}

// ---------------- phase B: per-item softmax + zj + combine ----------------
extern "C" __global__ void __launch_bounds__(256, 4)
aggregate(const int* __restrict__ nodes_v, const float* __restrict__ embed_i,
          const float* __restrict__ scg, const bf16* __restrict__ fj,
          const float* __restrict__ wr1_b, const float* __restrict__ wr2_b,
          const bf16* __restrict__ wt, float* __restrict__ out)
{
    __shared__ float qsh[4][64];
    __shared__ float zsh[4][64];
    __shared__ float z2sh[4][64];

    const int tid = threadIdx.x;
    const int lane = tid & 63, wave = tid >> 6;
    const int b = blockIdx.x * 4 + wave;
    const int d = lane;

    // softmax over scores (lane = neighbor index)
    float s = (lane < L_) ? scg[b * L_ + lane] : -1e30f;
    float mx = s;
#pragma unroll
    for (int off = 32; off; off >>= 1) mx = fmaxf(mx, __shfl_xor(mx, off));
    float e = (lane < L_) ? __expf(s - mx) : 0.f;
    float sum = e;
#pragma unroll
    for (int off = 32; off; off >>= 1) sum += __shfl_xor(sum, off);
    float mu = e / sum;

    // zj[d] = sum_l fjt[l][d] * mu[l]
    const bf16* fb = fj + b * L_ * 64;
    float z = 0.f;
#pragma unroll
    for (int l = 0; l < L_; ++l)
        z += (float)fb[l * 64 + d] * __shfl(mu, l);
    zsh[wave][d] = z;
    int v = nodes_v[b];
    qsh[wave][d] = embed_i[v * 64 + d];
    // same-wave LDS RAW (DS pipe in-order) -> no barrier

    // z2 = relu([zj|q] @ wr1 + b1)
    float accz = wr1_b[d];
    const bf16* r1 = wt + OFF_R1T + d * 128;
#pragma unroll
    for (int k8 = 0; k8 < 8; ++k8) {
        b16x8 wv = *(const b16x8*)(r1 + k8 * 8);
#pragma unroll
        for (int j = 0; j < 8; ++j) accz = fmaf((float)wv[j], zsh[wave][k8 * 8 + j], accz);
    }
#pragma unroll
    for (int k8 = 0; k8 < 8; ++k8) {
        b16x8 wv = *(const b16x8*)(r1 + 64 + k8 * 8);
#pragma unroll
        for (int j = 0; j < 8; ++j) accz = fmaf((float)wv[j], qsh[wave][k8 * 8 + j], accz);
    }
    z2sh[wave][d] = fmaxf(accz, 0.f);

    // out = relu(z2 @ wr2 + b2)
    float acco = wr2_b[d];
    const bf16* r2 = wt + OFF_R2T + d * 64;
#pragma unroll
    for (int k8 = 0; k8 < 8; ++k8) {
        b16x8 wv = *(const b16x8*)(r2 + k8 * 8);
#pragma unroll
        for (int j = 0; j < 8; ++j) acco = fmaf((float)wv[j], z2sh[wave][k8 * 8 + j], acco);
    }
    out[b * 64 + d] = fmaxf(acco, 0.f);
}

extern "C" void kernel_launch(void* const* d_in, const int* in_sizes, int n_in,
                              void* d_out, int out_size, void* d_ws, size_t ws_size,
                              hipStream_t stream)
{
    const int* nodes_v = (const int*)d_in[0];
    const int* neigh_u = (const int*)d_in[1];
    const int* neigh_r = (const int*)d_in[2];
    const float* embed_u = (const float*)d_in[3];
    const float* embed_i = (const float*)d_in[4];
    const float* embed_r = (const float*)d_in[5];
    const float* gv_w1  = (const float*)d_in[6];  const float* gv_b1 = (const float*)d_in[7];
    const float* gv_w2  = (const float*)d_in[8];  const float* gv_b2 = (const float*)d_in[9];
    const float* gv_w3  = (const float*)d_in[10]; const float* gv_b3 = (const float*)d_in[11];
    const float* att_w1 = (const float*)d_in[12]; const float* att_b1 = (const float*)d_in[13];
    const float* att_w2 = (const float*)d_in[14]; const float* att_b2 = (const float*)d_in[15];
    const float* att_w3 = (const float*)d_in[16]; const float* att_b3 = (const float*)d_in[17];
    const float* wr1_w  = (const float*)d_in[18]; const float* wr1_b = (const float*)d_in[19];
    const float* wr2_w  = (const float*)d_in[20]; const float* wr2_b = (const float*)d_in[21];
    (void)att_b3;  // softmax shift-invariance

    bf16*  wt     = (bf16*)d_ws;
    float* bias1p = (float*)((char*)d_ws + BIAS1P_BYTE);
    float* cft    = (float*)((char*)d_ws + C_BYTE);
    float* scg    = (float*)((char*)d_ws + SC_BYTE);
    bf16*  fjp    = (bf16*)((char*)d_ws + FJ_BYTE);

    prep_weights<<<(WT_TOTAL + 64 + 255) / 256, 256, 0, stream>>>(
        gv_w1, gv_w2, gv_w3, att_w1, att_w2, wr1_w, wr2_w, gv_b3, att_b1, wt, bias1p);
    prep_citem<<<(B_ * 64) / 256, 256, 0, stream>>>(nodes_v, embed_i, att_w1, bias1p, cft);
    dense_fwd<<<NROW / 128, 256, 0, stream>>>(neigh_u, neigh_r, embed_u, embed_r,
                                              gv_b1, gv_b2, gv_b3, att_b2, att_w3,
                                              wt, cft, fjp, scg);
    aggregate<<<B_ / 4, 256, 0, stream>>>(nodes_v, embed_i, scg, fjp,
                                          wr1_b, wr2_b, wt, (float*)d_out);
}

// Round 9
// 169.651 us; speedup vs baseline: 1.6092x; 1.0148x over previous
//
#include <hip/hip_runtime.h>

typedef __bf16 bf16;
typedef short s16x8 __attribute__((ext_vector_type(8)));   // 8 bf16 bit-patterns for MFMA frags
typedef __bf16 b16x8 __attribute__((ext_vector_type(8)));  // 8 bf16 for scalar convert paths
typedef float f32x4 __attribute__((ext_vector_type(4)));

#define B_   4096
#define L_   50
#define LP   64               // padded neighbors per item (rows 50..63 zero, masked in softmax)
#define SX   136              // X row stride (bf16): 128 + 8 pad

// ws layout, bf16 elems. Frag-major matrices: frag f = kt*4+nt is a contiguous
// 512-elem (1 KB) block; elem = f*512 + lane*8 + j -> W[k=kt*32+(lane>>4)*8+j][n=nt*16+(lane&15)].
#define OFF_W1F  0            // gv_w1  frag-major, K=128 (16 frags)
#define OFF_W2F  8192         // gv_w2  frag-major, K=64  (8 frags)
#define OFF_W3F  12288        // gv_w3  frag-major
#define OFF_WCF  16384        // (gv_w3 @ att_w1_top) frag-major
#define OFF_A2F  20480        // att_w2 frag-major
#define OFF_R1T  24576        // [64][128] wr1^T row-major (combine tail per-lane dots)
#define OFF_R2T  32768        // [64][64]  wr2^T row-major
#define WT_TOTAL 36864
// byte offsets in ws:
#define BIAS1P_BYTE 73728     // float[64]        att_b1 + gv_b3 @ att_w1_top
#define CQ_BYTE     73984     // float[4096][64]  q_b @ A1_bot  (bias1p added in dense)

#define PREP_W_BLOCKS 145     // ceil((WT_TOTAL+64)/256)
#define PREP_C_BLOCKS 1024    // 4096*64/256

__device__ __forceinline__ unsigned short f2b(float f) {
    __bf16 h = (__bf16)f;
    return __builtin_bit_cast(unsigned short, h);
}
__device__ __forceinline__ unsigned pack2(float a, float b) {
    return (unsigned)f2b(a) | ((unsigned)f2b(b) << 16);
}

// Dual-tile layer: O_t = act(A_t @ W + bias), two 16-row tiles share B-frags.
// B-frags from frag-major global weights: 1 KB coalesced load per (kt,nt), L1-hot.
// HW-verified layouts: A[m=lane&15][k=quad*8+j]; D col=lane&15, row=quad*4+reg.
template<int KT, bool RELU>
__device__ __forceinline__ void dual_layer(const bf16* A0, const bf16* A1,
                                           const bf16* __restrict__ Wf,
                                           const float* __restrict__ bias,
                                           bf16* O0, bf16* O1, int lane)
{
    const int m = lane & 15, quad = lane >> 4;
    f32x4 ac0[4] = {}, ac1[4] = {};
#pragma unroll
    for (int kt = 0; kt < KT; ++kt) {
        s16x8 a0 = *(const s16x8*)(A0 + m * SX + kt * 32 + quad * 8);
        s16x8 a1 = *(const s16x8*)(A1 + m * SX + kt * 32 + quad * 8);
#pragma unroll
        for (int nt = 0; nt < 4; ++nt) {
            s16x8 b = *(const s16x8*)(Wf + (kt * 4 + nt) * 512 + lane * 8);
            ac0[nt] = __builtin_amdgcn_mfma_f32_16x16x32_bf16(a0, b, ac0[nt], 0, 0, 0);
            ac1[nt] = __builtin_amdgcn_mfma_f32_16x16x32_bf16(a1, b, ac1[nt], 0, 0, 0);
        }
    }
#pragma unroll
    for (int nt = 0; nt < 4; ++nt) {
        int c = nt * 16 + m;
        float bv = bias[c];
#pragma unroll
        for (int r4 = 0; r4 < 4; ++r4) {
            float v0 = ac0[nt][r4] + bv, v1 = ac1[nt][r4] + bv;
            if (RELU) { v0 = fmaxf(v0, 0.f); v1 = fmaxf(v1, 0.f); }
            O0[(quad * 4 + r4) * SX + c] = (bf16)v0;
            O1[(quad * 4 + r4) * SX + c] = (bf16)v1;
        }
    }
}

// ---------------- prep (single launch): frag-major weights + bias1' + per-item cq ----------------
extern "C" __global__ void prep_all(const float* __restrict__ w1, const float* __restrict__ w2,
                                    const float* __restrict__ w3, const float* __restrict__ a1,
                                    const float* __restrict__ a2, const float* __restrict__ r1,
                                    const float* __restrict__ r2, const float* __restrict__ gb3,
                                    const float* __restrict__ ab1,
                                    const int* __restrict__ nodes_v, const float* __restrict__ embed_i,
                                    bf16* __restrict__ wt, float* __restrict__ bias1p,
                                    float* __restrict__ cq)
{
    if (blockIdx.x >= PREP_W_BLOCKS) {
        // cq[b][n] = q_b @ A1_bot   (independent of bias1p; dense adds bias1p)
        int gid = (blockIdx.x - PREP_W_BLOCKS) * 256 + threadIdx.x;   // 4096*64
        int b = gid >> 6, n = gid & 63;
        int v = nodes_v[b];
        const float* q = embed_i + v * 64;
        float s0 = 0.f, s1 = 0.f, s2 = 0.f, s3 = 0.f;
#pragma unroll
        for (int k = 0; k < 64; k += 4) {
            s0 = fmaf(q[k],     a1[(64 + k) * 64 + n],     s0);
            s1 = fmaf(q[k + 1], a1[(64 + k + 1) * 64 + n], s1);
            s2 = fmaf(q[k + 2], a1[(64 + k + 2) * 64 + n], s2);
            s3 = fmaf(q[k + 3], a1[(64 + k + 3) * 64 + n], s3);
        }
        cq[gid] = (s0 + s1) + (s2 + s3);
        return;
    }
    int i = blockIdx.x * 256 + threadIdx.x;
    if (i >= WT_TOTAL + 64) return;
    if (i >= WT_TOTAL) {                       // bias1'[n] = ab1[n] + sum_t gb3[t]*a1[t][n]
        int n = i - WT_TOTAL;
        float s0 = ab1[n], s1 = 0.f, s2 = 0.f, s3 = 0.f;
#pragma unroll
        for (int t = 0; t < 64; t += 4) {
            s0 = fmaf(gb3[t],     a1[t * 64 + n],       s0);
            s1 = fmaf(gb3[t + 1], a1[(t + 1) * 64 + n], s1);
            s2 = fmaf(gb3[t + 2], a1[(t + 2) * 64 + n], s2);
            s3 = fmaf(gb3[t + 3], a1[(t + 3) * 64 + n], s3);
        }
        bias1p[n] = (s0 + s1) + (s2 + s3);
        return;
    }
    float val;
    if (i < OFF_R1T) {
        int off, kind;   // 0=w1,1=w2,2=w3,3=wca,4=a2
        if      (i < OFF_W2F) { off = OFF_W1F; kind = 0; }
        else if (i < OFF_W3F) { off = OFF_W2F; kind = 1; }
        else if (i < OFF_WCF) { off = OFF_W3F; kind = 2; }
        else if (i < OFF_A2F) { off = OFF_WCF; kind = 3; }
        else                  { off = OFF_A2F; kind = 4; }
        int local = i - off;
        int f = local >> 9, lane = (local >> 3) & 63, j = local & 7;
        int kt = f >> 2, nt = f & 3, quad = lane >> 4, m = lane & 15;
        int k = kt * 32 + quad * 8 + j;
        int n = nt * 16 + m;
        if (kind == 0)      val = w1[k * 64 + n];
        else if (kind == 1) val = w2[k * 64 + n];
        else if (kind == 2) val = w3[k * 64 + n];
        else if (kind == 4) val = a2[k * 64 + n];
        else {                                  // wca[k][n] = (W3 @ A1_top)[k][n]
            float s0 = 0.f, s1 = 0.f, s2 = 0.f, s3 = 0.f;
#pragma unroll
            for (int t = 0; t < 64; t += 4) {
                float4 w = *(const float4*)(w3 + k * 64 + t);
                s0 = fmaf(w.x, a1[t * 64 + n],       s0);
                s1 = fmaf(w.y, a1[(t + 1) * 64 + n], s1);
                s2 = fmaf(w.z, a1[(t + 2) * 64 + n], s2);
                s3 = fmaf(w.w, a1[(t + 3) * 64 + n], s3);
            }
            val = (s0 + s1) + (s2 + s3);
        }
    }
    else if (i < OFF_R2T) { int li = i - OFF_R1T; int n = li >> 7, k = li & 127; val = r1[k * 64 + n]; }
    else                  { int li = i - OFF_R2T; int n = li >> 6, k = li & 63;  val = r2[k * 64 + n]; }
    wt[i] = (bf16)val;
}

// ---------------- fused phase: 2 items x 64 padded rows per block, full pipeline to out ----------------
// 2048 blocks, 4 waves x two 16-row tiles. Items never straddle blocks -> softmax/zj/combine in-block.
extern "C" __global__ void __launch_bounds__(256, 2)
dense_fused(const int* __restrict__ nodes_v, const int* __restrict__ neigh_u,
            const int* __restrict__ neigh_r,
            const float* __restrict__ embed_u, const float* __restrict__ embed_i,
            const float* __restrict__ embed_r,
            const float* __restrict__ gv_b1, const float* __restrict__ gv_b2,
            const float* __restrict__ gv_b3,
            const float* __restrict__ att_b2, const float* __restrict__ att_w3,
            const float* __restrict__ wr1_b, const float* __restrict__ wr2_b,
            const bf16* __restrict__ wt, const float* __restrict__ cq,
            const float* __restrict__ bias1p, float* __restrict__ out)
{
    __shared__ __align__(16) bf16 Xs[128 * SX];     // 34816 B
    __shared__ float csS[128];                      // att1 bias per item (2 x 64)
    __shared__ float qsh[128];                      // q per item (2 x 64)
    __shared__ float scs[128];                      // scores (2 x 64); reused as z2-share in tail
    __shared__ float zp[4 * 64];                    // zj partials per wave

    const int tid = threadIdx.x;
    const int lane = tid & 63, wave = tid >> 6;
    const int m = lane & 15, quad = lane >> 4;
    const int b0 = blockIdx.x * 2;                  // two items per block
    const int rw0 = wave * 32;                      // wave-local rows (item = rw0>>6)

    // stage per-item att1 bias (cq + bias1p) and q
    if (tid < 128) {
        int item = tid >> 6, n = tid & 63;
        csS[tid] = cq[(b0 + item) * 64 + n] + bias1p[n];
        qsh[tid] = embed_i[nodes_v[b0 + item] * 64 + n];
    }

    // wave-local gather of 32 rows: pt -> X[:,0:64], er -> X[:,64:128]; pad rows (l>=50) zeroed
    {
        const int rsub = lane >> 4;   // 4 rows per iter
        const int c = lane & 15;      // 16B chunk
#pragma unroll
        for (int it = 0; it < 8; ++it) {
            int rloc = rw0 + it * 4 + rsub;
            int item = rloc >> 6, l = rloc & 63;
            float4 vu = make_float4(0.f, 0.f, 0.f, 0.f), vr = vu;
            if (l < L_) {
                int u = neigh_u[(b0 + item) * L_ + l];
                int r = neigh_r[(b0 + item) * L_ + l];
                vu = *(const float4*)(embed_u + u * 64 + c * 4);
                vr = *(const float4*)(embed_r + r * 64 + c * 4);
            }
            uint2 pu, pr;
            pu.x = pack2(vu.x, vu.y); pu.y = pack2(vu.z, vu.w);
            pr.x = pack2(vr.x, vr.y); pr.y = pack2(vr.z, vr.w);
            *(uint2*)(Xs + rloc * SX + c * 4) = pu;
            *(uint2*)(Xs + rloc * SX + 64 + c * 4) = pr;
        }
    }

    bf16* X0 = Xs + rw0 * SX;          // tile 0 rows
    bf16* X1 = Xs + (rw0 + 16) * SX;   // tile 1 rows

    // gv1: X[:,0:128] -> h1 -> X[:,64:128]  (er dead after reads; same-wave WAR safe)
    dual_layer<4, true>(X0, X1, wt + OFF_W1F, gv_b1, X0 + 64, X1 + 64, lane);

    __syncthreads();   // csS + qsh visible

    // gv2: h1 -> h2 -> X[:,0:64]
    dual_layer<2, true>(X0 + 64, X1 + 64, wt + OFF_W2F, gv_b2, X0, X1, lane);

    // fused gv3 + att1': consume h2; fjt -> X[:,64:128], att1h -> X[:,0:64]
    {
        const bf16* w3f = wt + OFF_W3F;
        const bf16* wcf = wt + OFF_WCF;
        const int io = (rw0 >> 6) * 64;   // this wave's item offset into csS (wave-uniform)
        f32x4 aF0[4] = {}, aF1[4] = {}, aA0[4] = {}, aA1[4] = {};
#pragma unroll
        for (int kt = 0; kt < 2; ++kt) {
            s16x8 a0 = *(const s16x8*)(X0 + m * SX + kt * 32 + quad * 8);
            s16x8 a1 = *(const s16x8*)(X1 + m * SX + kt * 32 + quad * 8);
#pragma unroll
            for (int nt = 0; nt < 4; ++nt) {
                s16x8 bF = *(const s16x8*)(w3f + (kt * 4 + nt) * 512 + lane * 8);
                s16x8 bA = *(const s16x8*)(wcf + (kt * 4 + nt) * 512 + lane * 8);
                aF0[nt] = __builtin_amdgcn_mfma_f32_16x16x32_bf16(a0, bF, aF0[nt], 0, 0, 0);
                aF1[nt] = __builtin_amdgcn_mfma_f32_16x16x32_bf16(a1, bF, aF1[nt], 0, 0, 0);
                aA0[nt] = __builtin_amdgcn_mfma_f32_16x16x32_bf16(a0, bA, aA0[nt], 0, 0, 0);
                aA1[nt] = __builtin_amdgcn_mfma_f32_16x16x32_bf16(a1, bA, aA1[nt], 0, 0, 0);
            }
        }
#pragma unroll
        for (int nt = 0; nt < 4; ++nt) {
            int c = nt * 16 + m;
            float b3v = gv_b3[c], b1v = csS[io + c];
#pragma unroll
            for (int r4 = 0; r4 < 4; ++r4) {
                int rl0 = rw0 + quad * 4 + r4, rl1 = rl0 + 16;
                Xs[rl0 * SX + 64 + c] = (bf16)(aF0[nt][r4] + b3v);
                Xs[rl1 * SX + 64 + c] = (bf16)(aF1[nt][r4] + b3v);
                Xs[rl0 * SX + c] = (bf16)fmaxf(aA0[nt][r4] + b1v, 0.f);
                Xs[rl1 * SX + c] = (bf16)fmaxf(aA1[nt][r4] + b1v, 0.f);
            }
        }
    }

    // att2 in regs + relu + dot(att_w3) + 16-lane reduce -> scores (LDS)
    {
        const bf16* a2f = wt + OFF_A2F;
        f32x4 ac0[4] = {}, ac1[4] = {};
#pragma unroll
        for (int kt = 0; kt < 2; ++kt) {
            s16x8 a0 = *(const s16x8*)(X0 + m * SX + kt * 32 + quad * 8);
            s16x8 a1 = *(const s16x8*)(X1 + m * SX + kt * 32 + quad * 8);
#pragma unroll
            for (int nt = 0; nt < 4; ++nt) {
                s16x8 b = *(const s16x8*)(a2f + (kt * 4 + nt) * 512 + lane * 8);
                ac0[nt] = __builtin_amdgcn_mfma_f32_16x16x32_bf16(a0, b, ac0[nt], 0, 0, 0);
                ac1[nt] = __builtin_amdgcn_mfma_f32_16x16x32_bf16(a1, b, ac1[nt], 0, 0, 0);
            }
        }
        float s0[4] = {0.f, 0.f, 0.f, 0.f}, s1[4] = {0.f, 0.f, 0.f, 0.f};
#pragma unroll
        for (int nt = 0; nt < 4; ++nt) {
            int c = nt * 16 + m;
            float b2v = att_b2[c], w3v = att_w3[c];
#pragma unroll
            for (int r4 = 0; r4 < 4; ++r4) {
                s0[r4] += fmaxf(ac0[nt][r4] + b2v, 0.f) * w3v;
                s1[r4] += fmaxf(ac1[nt][r4] + b2v, 0.f) * w3v;
            }
        }
#pragma unroll
        for (int mask = 1; mask < 16; mask <<= 1)
#pragma unroll
            for (int r4 = 0; r4 < 4; ++r4) {
                s0[r4] += __shfl_xor(s0[r4], mask);
                s1[r4] += __shfl_xor(s1[r4], mask);
            }
        if (m == 0) {
#pragma unroll
            for (int r4 = 0; r4 < 4; ++r4) {
                scs[rw0 + quad * 4 + r4] = s0[r4];
                scs[rw0 + 16 + quad * 4 + r4] = s1[r4];
            }
        }
    }
    __syncthreads();   // scores visible (fjt stays wave-local)

    // per-wave softmax of this wave's item (lane = neighbor l; pad lanes masked)
    {
        const int io = (rw0 >> 6) * 64;
        float s = (lane < L_) ? scs[io + lane] : -1e30f;
        float mx = s;
#pragma unroll
        for (int off = 32; off; off >>= 1) mx = fmaxf(mx, __shfl_xor(mx, off));
        float e = (lane < L_) ? __expf(s - mx) : 0.f;
        float sum = e;
#pragma unroll
        for (int off = 32; off; off >>= 1) sum += __shfl_xor(sum, off);
        float mu = e / sum;   // mu[lane] of this item

        // zj partial over this wave's 32 fjt rows (l = rw0&63 .. +31)
        float z = 0.f;
#pragma unroll
        for (int i = 0; i < 32; ++i) {
            int rloc = rw0 + i;
            z += (float)Xs[rloc * SX + 64 + lane] * __shfl(mu, (rloc & 63));
        }
        zp[wave * 64 + lane] = z;
    }
    __syncthreads();

    // combine tail: wave 0 -> item 0, wave 2 -> item 1
    if ((wave & 1) == 0) {
        const int item = wave >> 1;
        const int d = lane;
        float z = zp[(wave + 0) * 64 + d] + zp[(wave + 1) * 64 + d];
        float* zsh = scs + item * 64;   // scores dead after softmax; reuse (same-wave in-order)
        zsh[d] = z;

        // z2 = relu([zj|q] @ wr1 + b1)
        float accz = wr1_b[d];
        const bf16* r1 = wt + OFF_R1T + d * 128;
#pragma unroll
        for (int k8 = 0; k8 < 8; ++k8) {
            b16x8 wv = *(const b16x8*)(r1 + k8 * 8);
#pragma unroll
            for (int j = 0; j < 8; ++j) accz = fmaf((float)wv[j], zsh[k8 * 8 + j], accz);
        }
#pragma unroll
        for (int k8 = 0; k8 < 8; ++k8) {
            b16x8 wv = *(const b16x8*)(r1 + 64 + k8 * 8);
#pragma unroll
            for (int j = 0; j < 8; ++j) accz = fmaf((float)wv[j], qsh[item * 64 + k8 * 8 + j], accz);
        }
        float* z2sh = zp + wave * 64;   // reuse own partial slot (same-wave in-order)
        z2sh[d] = fmaxf(accz, 0.f);

        // out = relu(z2 @ wr2 + b2)
        float acco = wr2_b[d];
        const bf16* r2 = wt + OFF_R2T + d * 64;
#pragma unroll
        for (int k8 = 0; k8 < 8; ++k8) {
            b16x8 wv = *(const b16x8*)(r2 + k8 * 8);
#pragma unroll
            for (int j = 0; j < 8; ++j) acco = fmaf((float)wv[j], z2sh[k8 * 8 + j], acco);
        }
        out[(b0 + item) * 64 + d] = fmaxf(acco, 0.f);
    }
}

extern "C" void kernel_launch(void* const* d_in, const int* in_sizes, int n_in,
                              void* d_out, int out_size, void* d_ws, size_t ws_size,
                              hipStream_t stream)
{
    const int* nodes_v = (const int*)d_in[0];
    const int* neigh_u = (const int*)d_in[1];
    const int* neigh_r = (const int*)d_in[2];
    const float* embed_u = (const float*)d_in[3];
    const float* embed_i = (const float*)d_in[4];
    const float* embed_r = (const float*)d_in[5];
    const float* gv_w1  = (const float*)d_in[6];  const float* gv_b1 = (const float*)d_in[7];
    const float* gv_w2  = (const float*)d_in[8];  const float* gv_b2 = (const float*)d_in[9];
    const float* gv_w3  = (const float*)d_in[10]; const float* gv_b3 = (const float*)d_in[11];
    const float* att_w1 = (const float*)d_in[12]; const float* att_b1 = (const float*)d_in[13];
    const float* att_w2 = (const float*)d_in[14]; const float* att_b2 = (const float*)d_in[15];
    const float* att_w3 = (const float*)d_in[16]; const float* att_b3 = (const float*)d_in[17];
    const float* wr1_w  = (const float*)d_in[18]; const float* wr1_b = (const float*)d_in[19];
    const float* wr2_w  = (const float*)d_in[20]; const float* wr2_b = (const float*)d_in[21];
    (void)att_b3;  // softmax shift-invariance

    bf16*  wt     = (bf16*)d_ws;
    float* bias1p = (float*)((char*)d_ws + BIAS1P_BYTE);
    float* cq     = (float*)((char*)d_ws + CQ_BYTE);

    prep_all<<<PREP_W_BLOCKS + PREP_C_BLOCKS, 256, 0, stream>>>(
        gv_w1, gv_w2, gv_w3, att_w1, att_w2, wr1_w, wr2_w, gv_b3, att_b1,
        nodes_v, embed_i, wt, bias1p, cq);
    dense_fused<<<B_ / 2, 256, 0, stream>>>(nodes_v, neigh_u, neigh_r,
                                            embed_u, embed_i, embed_r,
                                            gv_b1, gv_b2, gv_b3, att_b2, att_w3,
                                            wr1_b, wr2_b, wt, cq, bias1p, (float*)d_out);
}

// Round 10
// 169.329 us; speedup vs baseline: 1.6122x; 1.0019x over previous
//
#include <hip/hip_runtime.h>

typedef __bf16 bf16;
typedef short s16x8 __attribute__((ext_vector_type(8)));   // 8 bf16 bit-patterns for MFMA frags
typedef __bf16 b16x8 __attribute__((ext_vector_type(8)));  // 8 bf16 for scalar convert paths
typedef float f32x4 __attribute__((ext_vector_type(4)));

#define B_   4096
#define L_   50
#define SH   72               // H row stride (bf16): 64 + 8 pad (144 B -> 2-way bank alias, free)

// ws layout, bf16 elems. Frag-major matrices: frag f = kt*4+nt is a contiguous
// 512-elem (1 KB) block; elem = f*512 + lane*8 + j -> W[k=kt*32+(lane>>4)*8+j][n=nt*16+(lane&15)].
#define OFF_W1F  0            // gv_w1  frag-major, K=128 (16 frags)
#define OFF_W2F  8192         // gv_w2  frag-major, K=64  (8 frags)
#define OFF_W3F  12288        // gv_w3  frag-major
#define OFF_WCF  16384        // (gv_w3 @ att_w1_top) frag-major
#define OFF_A2F  20480        // att_w2 frag-major
#define OFF_R1T  24576        // [64][128] wr1^T row-major (combine tail per-lane dots)
#define OFF_R2T  32768        // [64][64]  wr2^T row-major
#define WT_TOTAL 36864
// byte offsets in ws:
#define BIAS1P_BYTE 73728     // float[64]        att_b1 + gv_b3 @ att_w1_top
#define CQ_BYTE     73984     // float[4096][64]  q_b @ A1_bot  (bias1p added in dense)

#define PREP_W_BLOCKS 145     // ceil((WT_TOTAL+64)/256)
#define PREP_C_BLOCKS 1024    // 4096*64/256

__device__ __forceinline__ unsigned short f2b(float f) {
    __bf16 h = (__bf16)f;
    return __builtin_bit_cast(unsigned short, h);
}
__device__ __forceinline__ unsigned pack2(float a, float b) {
    return (unsigned)f2b(a) | ((unsigned)f2b(b) << 16);
}
__device__ __forceinline__ s16x8 mkfrag(float4 a, float4 b) {
    union { s16x8 v; unsigned u[4]; } r;
    r.u[0] = pack2(a.x, a.y); r.u[1] = pack2(a.z, a.w);
    r.u[2] = pack2(b.x, b.y); r.u[3] = pack2(b.z, b.w);
    return r.v;
}
__device__ __forceinline__ f32x4 mfma16(s16x8 a, s16x8 b, f32x4 c) {
    return __builtin_amdgcn_mfma_f32_16x16x32_bf16(a, b, c, 0, 0, 0);
}

// Dual-tile K=64 layer from LDS: O_t = act(A_t @ W + bias). In-place (O==A region) is
// same-wave WAR-safe: all frag reads issue before epilogue writes, DS pipe in-order per wave.
// HW-verified layouts: A[m=lane&15][k=quad*8+j]; D col=lane&15, row=quad*4+reg.
template<bool RELU>
__device__ __forceinline__ void dual_layer_lds(const bf16* A0, const bf16* A1,
                                               const bf16* __restrict__ Wf,
                                               const float* __restrict__ bias,
                                               bf16* O0, bf16* O1, int lane)
{
    const int m = lane & 15, quad = lane >> 4;
    f32x4 ac0[4] = {}, ac1[4] = {};
#pragma unroll
    for (int kt = 0; kt < 2; ++kt) {
        s16x8 a0 = *(const s16x8*)(A0 + m * SH + kt * 32 + quad * 8);
        s16x8 a1 = *(const s16x8*)(A1 + m * SH + kt * 32 + quad * 8);
#pragma unroll
        for (int nt = 0; nt < 4; ++nt) {
            s16x8 b = *(const s16x8*)(Wf + (kt * 4 + nt) * 512 + lane * 8);
            ac0[nt] = mfma16(a0, b, ac0[nt]);
            ac1[nt] = mfma16(a1, b, ac1[nt]);
        }
    }
#pragma unroll
    for (int nt = 0; nt < 4; ++nt) {
        int c = nt * 16 + m;
        float bv = bias[c];
#pragma unroll
        for (int r4 = 0; r4 < 4; ++r4) {
            float v0 = ac0[nt][r4] + bv, v1 = ac1[nt][r4] + bv;
            if (RELU) { v0 = fmaxf(v0, 0.f); v1 = fmaxf(v1, 0.f); }
            O0[(quad * 4 + r4) * SH + c] = (bf16)v0;
            O1[(quad * 4 + r4) * SH + c] = (bf16)v1;
        }
    }
}

// ---------------- prep (single launch): frag-major weights + bias1' + per-item cq ----------------
extern "C" __global__ void prep_all(const float* __restrict__ w1, const float* __restrict__ w2,
                                    const float* __restrict__ w3, const float* __restrict__ a1,
                                    const float* __restrict__ a2, const float* __restrict__ r1,
                                    const float* __restrict__ r2, const float* __restrict__ gb3,
                                    const float* __restrict__ ab1,
                                    const int* __restrict__ nodes_v, const float* __restrict__ embed_i,
                                    bf16* __restrict__ wt, float* __restrict__ bias1p,
                                    float* __restrict__ cq)
{
    if (blockIdx.x >= PREP_W_BLOCKS) {
        // cq[b][n] = q_b @ A1_bot   (bias1p added in dense)
        int gid = (blockIdx.x - PREP_W_BLOCKS) * 256 + threadIdx.x;   // 4096*64
        int b = gid >> 6, n = gid & 63;
        int v = nodes_v[b];
        const float* q = embed_i + v * 64;
        float s0 = 0.f, s1 = 0.f, s2 = 0.f, s3 = 0.f;
#pragma unroll
        for (int k = 0; k < 64; k += 4) {
            s0 = fmaf(q[k],     a1[(64 + k) * 64 + n],     s0);
            s1 = fmaf(q[k + 1], a1[(64 + k + 1) * 64 + n], s1);
            s2 = fmaf(q[k + 2], a1[(64 + k + 2) * 64 + n], s2);
            s3 = fmaf(q[k + 3], a1[(64 + k + 3) * 64 + n], s3);
        }
        cq[gid] = (s0 + s1) + (s2 + s3);
        return;
    }
    int i = blockIdx.x * 256 + threadIdx.x;
    if (i >= WT_TOTAL + 64) return;
    if (i >= WT_TOTAL) {                       // bias1'[n] = ab1[n] + sum_t gb3[t]*a1[t][n]
        int n = i - WT_TOTAL;
        float s0 = ab1[n], s1 = 0.f, s2 = 0.f, s3 = 0.f;
#pragma unroll
        for (int t = 0; t < 64; t += 4) {
            s0 = fmaf(gb3[t],     a1[t * 64 + n],       s0);
            s1 = fmaf(gb3[t + 1], a1[(t + 1) * 64 + n], s1);
            s2 = fmaf(gb3[t + 2], a1[(t + 2) * 64 + n], s2);
            s3 = fmaf(gb3[t + 3], a1[(t + 3) * 64 + n], s3);
        }
        bias1p[n] = (s0 + s1) + (s2 + s3);
        return;
    }
    float val;
    if (i < OFF_R1T) {
        int off, kind;   // 0=w1,1=w2,2=w3,3=wca,4=a2
        if      (i < OFF_W2F) { off = OFF_W1F; kind = 0; }
        else if (i < OFF_W3F) { off = OFF_W2F; kind = 1; }
        else if (i < OFF_WCF) { off = OFF_W3F; kind = 2; }
        else if (i < OFF_A2F) { off = OFF_WCF; kind = 3; }
        else                  { off = OFF_A2F; kind = 4; }
        int local = i - off;
        int f = local >> 9, lane = (local >> 3) & 63, j = local & 7;
        int kt = f >> 2, nt = f & 3, quad = lane >> 4, m = lane & 15;
        int k = kt * 32 + quad * 8 + j;
        int n = nt * 16 + m;
        if (kind == 0)      val = w1[k * 64 + n];
        else if (kind == 1) val = w2[k * 64 + n];
        else if (kind == 2) val = w3[k * 64 + n];
        else if (kind == 4) val = a2[k * 64 + n];
        else {                                  // wca[k][n] = (W3 @ A1_top)[k][n]
            float s0 = 0.f, s1 = 0.f, s2 = 0.f, s3 = 0.f;
#pragma unroll
            for (int t = 0; t < 64; t += 4) {
                float4 w = *(const float4*)(w3 + k * 64 + t);
                s0 = fmaf(w.x, a1[t * 64 + n],       s0);
                s1 = fmaf(w.y, a1[(t + 1) * 64 + n], s1);
                s2 = fmaf(w.z, a1[(t + 2) * 64 + n], s2);
                s3 = fmaf(w.w, a1[(t + 3) * 64 + n], s3);
            }
            val = (s0 + s1) + (s2 + s3);
        }
    }
    else if (i < OFF_R2T) { int li = i - OFF_R1T; int n = li >> 7, k = li & 127; val = r1[k * 64 + n]; }
    else                  { int li = i - OFF_R2T; int n = li >> 6, k = li & 63;  val = r2[k * 64 + n]; }
    wt[i] = (bf16)val;
}

// ---------------- fused: 2 items x 64 padded rows/block; gv1 from regs; fjt in regs ----------------
// LDS ~20.5 KB -> 7 blocks/CU cap; VGPR-capped ~5 waves/SIMD expected.
extern "C" __global__ void __launch_bounds__(256, 2)
dense_fused(const int* __restrict__ nodes_v, const int* __restrict__ neigh_u,
            const int* __restrict__ neigh_r,
            const float* __restrict__ embed_u, const float* __restrict__ embed_i,
            const float* __restrict__ embed_r,
            const float* __restrict__ gv_b1, const float* __restrict__ gv_b2,
            const float* __restrict__ gv_b3,
            const float* __restrict__ att_b2, const float* __restrict__ att_w3,
            const float* __restrict__ wr1_b, const float* __restrict__ wr2_b,
            const bf16* __restrict__ wt, const float* __restrict__ cq,
            const float* __restrict__ bias1p, float* __restrict__ out)
{
    __shared__ __align__(16) bf16 H[128 * SH];      // 18432 B: h1 -> h2 -> att1h (same-wave reuse)
    __shared__ float csS[128];                      // att1 bias per item (2 x 64)
    __shared__ float qsh[128];                      // q per item
    __shared__ float scs[128];                      // scores; reused as zj-share in tail
    __shared__ float zp[4 * 64];                    // zj partials per wave

    const int tid = threadIdx.x;
    const int lane = tid & 63, wave = tid >> 6;
    const int m = lane & 15, quad = lane >> 4;
    const int b0 = blockIdx.x * 2;
    const int rw0 = wave * 32;                      // wave's rows in [0,128)
    const int item_w = rw0 >> 6;                    // this wave's item (0/1)
    const int lbase = rw0 & 63;                     // neighbor offset within item (0/32)

    // stage per-item att1 bias (cq + bias1p) and q
    if (tid < 128) {
        int item = tid >> 6, n = tid & 63;
        csS[tid] = cq[(b0 + item) * 64 + n] + bias1p[n];
        qsh[tid] = embed_i[nodes_v[b0 + item] * 64 + n];
    }

    // neighbor indices for this lane's two A-frag rows (clamped; pad rows masked at softmax)
    const int bw = b0 + item_w;
    const int l0 = min(lbase + m, L_ - 1);
    const int l1 = min(lbase + 16 + m, L_ - 1);
    const int u0 = neigh_u[bw * L_ + l0], u1 = neigh_u[bw * L_ + l1];
    const int v0 = neigh_r[bw * L_ + l0], v1 = neigh_r[bw * L_ + l1];

    bf16* Hw = H + rw0 * SH;   // this wave's 32 rows
    bf16* H0 = Hw;             // tile 0
    bf16* H1 = Hw + 16 * SH;   // tile 1

    // ---- gv1 straight from global regs: h1 = relu([pt|er] @ W1 + b1) -> H ----
    {
        const float* b00 = embed_u + u0 * 64;   // kt 0,1: pt
        const float* b01 = embed_u + u1 * 64;
        const float* b10 = embed_r + v0 * 64;   // kt 2,3: er
        const float* b11 = embed_r + v1 * 64;
        f32x4 ac0[4] = {}, ac1[4] = {};
#pragma unroll
        for (int kt = 0; kt < 4; ++kt) {
            const float* s0p = (kt < 2 ? b00 : b10) + (kt & 1) * 32 + quad * 8;
            const float* s1p = (kt < 2 ? b01 : b11) + (kt & 1) * 32 + quad * 8;
            float4 a0a = *(const float4*)s0p, a0b = *(const float4*)(s0p + 4);
            float4 a1a = *(const float4*)s1p, a1b = *(const float4*)(s1p + 4);
            s16x8 a0 = mkfrag(a0a, a0b);
            s16x8 a1 = mkfrag(a1a, a1b);
#pragma unroll
            for (int nt = 0; nt < 4; ++nt) {
                s16x8 b = *(const s16x8*)(wt + OFF_W1F + (kt * 4 + nt) * 512 + lane * 8);
                ac0[nt] = mfma16(a0, b, ac0[nt]);
                ac1[nt] = mfma16(a1, b, ac1[nt]);
            }
        }
#pragma unroll
        for (int nt = 0; nt < 4; ++nt) {
            int c = nt * 16 + m;
            float bv = gv_b1[c];
#pragma unroll
            for (int r4 = 0; r4 < 4; ++r4) {
                H0[(quad * 4 + r4) * SH + c] = (bf16)fmaxf(ac0[nt][r4] + bv, 0.f);
                H1[(quad * 4 + r4) * SH + c] = (bf16)fmaxf(ac1[nt][r4] + bv, 0.f);
            }
        }
    }

    // gv2: h1 -> h2 (in-place region reuse, same-wave WAR safe)
    dual_layer_lds<true>(H0, H1, wt + OFF_W2F, gv_b2, H0, H1, lane);

    __syncthreads();   // csS/qsh visible (needed by gv3+att1 epilogue / tail)

    // ---- fused gv3 + att1': consume h2; fjt stays in regs (aF), att1h -> H ----
    f32x4 aF0[4] = {}, aF1[4] = {};
    {
        const bf16* w3f = wt + OFF_W3F;
        const bf16* wcf = wt + OFF_WCF;
        f32x4 aA0[4] = {}, aA1[4] = {};
#pragma unroll
        for (int kt = 0; kt < 2; ++kt) {
            s16x8 a0 = *(const s16x8*)(H0 + m * SH + kt * 32 + quad * 8);
            s16x8 a1 = *(const s16x8*)(H1 + m * SH + kt * 32 + quad * 8);
#pragma unroll
            for (int nt = 0; nt < 4; ++nt) {
                s16x8 bF = *(const s16x8*)(w3f + (kt * 4 + nt) * 512 + lane * 8);
                s16x8 bA = *(const s16x8*)(wcf + (kt * 4 + nt) * 512 + lane * 8);
                aF0[nt] = mfma16(a0, bF, aF0[nt]);
                aF1[nt] = mfma16(a1, bF, aF1[nt]);
                aA0[nt] = mfma16(a0, bA, aA0[nt]);
                aA1[nt] = mfma16(a1, bA, aA1[nt]);
            }
        }
        // write only att1h (relu(aA + per-item bias)); aF kept in regs (bias b3 folded into zj)
#pragma unroll
        for (int nt = 0; nt < 4; ++nt) {
            int c = nt * 16 + m;
            float b1v = csS[item_w * 64 + c];
#pragma unroll
            for (int r4 = 0; r4 < 4; ++r4) {
                H0[(quad * 4 + r4) * SH + c] = (bf16)fmaxf(aA0[nt][r4] + b1v, 0.f);
                H1[(quad * 4 + r4) * SH + c] = (bf16)fmaxf(aA1[nt][r4] + b1v, 0.f);
            }
        }
    }

    // ---- att2 + relu + dot(att_w3) + quad-reduce -> scores (LDS) ----
    {
        const bf16* a2f = wt + OFF_A2F;
        f32x4 ac0[4] = {}, ac1[4] = {};
#pragma unroll
        for (int kt = 0; kt < 2; ++kt) {
            s16x8 a0 = *(const s16x8*)(H0 + m * SH + kt * 32 + quad * 8);
            s16x8 a1 = *(const s16x8*)(H1 + m * SH + kt * 32 + quad * 8);
#pragma unroll
            for (int nt = 0; nt < 4; ++nt) {
                s16x8 b = *(const s16x8*)(a2f + (kt * 4 + nt) * 512 + lane * 8);
                ac0[nt] = mfma16(a0, b, ac0[nt]);
                ac1[nt] = mfma16(a1, b, ac1[nt]);
            }
        }
        float s0[4] = {0.f, 0.f, 0.f, 0.f}, s1[4] = {0.f, 0.f, 0.f, 0.f};
#pragma unroll
        for (int nt = 0; nt < 4; ++nt) {
            int c = nt * 16 + m;
            float b2v = att_b2[c], w3v = att_w3[c];
#pragma unroll
            for (int r4 = 0; r4 < 4; ++r4) {
                s0[r4] += fmaxf(ac0[nt][r4] + b2v, 0.f) * w3v;
                s1[r4] += fmaxf(ac1[nt][r4] + b2v, 0.f) * w3v;
            }
        }
#pragma unroll
        for (int mask = 1; mask < 16; mask <<= 1)
#pragma unroll
            for (int r4 = 0; r4 < 4; ++r4) {
                s0[r4] += __shfl_xor(s0[r4], mask);
                s1[r4] += __shfl_xor(s1[r4], mask);
            }
        if (m == 0) {
#pragma unroll
            for (int r4 = 0; r4 < 4; ++r4) {
                scs[item_w * 64 + lbase + quad * 4 + r4] = s0[r4];
                scs[item_w * 64 + lbase + 16 + quad * 4 + r4] = s1[r4];
            }
        }
    }
    __syncthreads();   // all 64 scores of each item visible

    // ---- per-wave softmax + zj from aF regs (fjt never in LDS) ----
    {
        float s = (lane < L_) ? scs[item_w * 64 + lane] : -1e30f;
        float mx = s;
#pragma unroll
        for (int off = 32; off; off >>= 1) mx = fmaxf(mx, __shfl_xor(mx, off));
        float e = (lane < L_) ? __expf(s - mx) : 0.f;
        float sum = e;
#pragma unroll
        for (int off = 32; off; off >>= 1) sum += __shfl_xor(sum, off);
        float mu = e / sum;   // mu[lane] of this wave's item

        float z[4] = {0.f, 0.f, 0.f, 0.f};
#pragma unroll
        for (int r4 = 0; r4 < 4; ++r4) {
            float m0 = __shfl(mu, lbase + quad * 4 + r4);
            float m1 = __shfl(mu, lbase + 16 + quad * 4 + r4);
#pragma unroll
            for (int nt = 0; nt < 4; ++nt)
                z[nt] += aF0[nt][r4] * m0 + aF1[nt][r4] * m1;
        }
#pragma unroll
        for (int nt = 0; nt < 4; ++nt) {
            z[nt] += __shfl_xor(z[nt], 16);
            z[nt] += __shfl_xor(z[nt], 32);
        }
        if (quad == 0) {
#pragma unroll
            for (int nt = 0; nt < 4; ++nt) zp[wave * 64 + nt * 16 + m] = z[nt];
        }
    }
    __syncthreads();

    // ---- combine tail: wave 0 -> item 0, wave 2 -> item 1 ----
    if ((wave & 1) == 0) {
        const int item = wave >> 1;
        const int d = lane;
        // zj = sum of the item's two wave-partials + gv_b3 (sum(mu)==1 folds fjt bias to one add)
        float z = zp[wave * 64 + d] + zp[wave * 64 + 64 + d] + gv_b3[d];
        float* zsh = scs + item * 64;   // scores dead; reuse (same-wave in-order)
        zsh[d] = z;

        // z2 = relu([zj|q] @ wr1 + b1)
        float accz = wr1_b[d];
        const bf16* r1 = wt + OFF_R1T + d * 128;
#pragma unroll
        for (int k8 = 0; k8 < 8; ++k8) {
            b16x8 wv = *(const b16x8*)(r1 + k8 * 8);
#pragma unroll
            for (int j = 0; j < 8; ++j) accz = fmaf((float)wv[j], zsh[k8 * 8 + j], accz);
        }
#pragma unroll
        for (int k8 = 0; k8 < 8; ++k8) {
            b16x8 wv = *(const b16x8*)(r1 + 64 + k8 * 8);
#pragma unroll
            for (int j = 0; j < 8; ++j) accz = fmaf((float)wv[j], qsh[item * 64 + k8 * 8 + j], accz);
        }
        float* z2sh = zp + wave * 64;   // reuse own partial slot (same-wave in-order)
        z2sh[d] = fmaxf(accz, 0.f);

        // out = relu(z2 @ wr2 + b2)
        float acco = wr2_b[d];
        const bf16* r2 = wt + OFF_R2T + d * 64;
#pragma unroll
        for (int k8 = 0; k8 < 8; ++k8) {
            b16x8 wv = *(const b16x8*)(r2 + k8 * 8);
#pragma unroll
            for (int j = 0; j < 8; ++j) acco = fmaf((float)wv[j], z2sh[k8 * 8 + j], acco);
        }
        out[(b0 + item) * 64 + d] = fmaxf(acco, 0.f);
    }
}

extern "C" void kernel_launch(void* const* d_in, const int* in_sizes, int n_in,
                              void* d_out, int out_size, void* d_ws, size_t ws_size,
                              hipStream_t stream)
{
    const int* nodes_v = (const int*)d_in[0];
    const int* neigh_u = (const int*)d_in[1];
    const int* neigh_r = (const int*)d_in[2];
    const float* embed_u = (const float*)d_in[3];
    const float* embed_i = (const float*)d_in[4];
    const float* embed_r = (const float*)d_in[5];
    const float* gv_w1  = (const float*)d_in[6];  const float* gv_b1 = (const float*)d_in[7];
    const float* gv_w2  = (const float*)d_in[8];  const float* gv_b2 = (const float*)d_in[9];
    const float* gv_w3  = (const float*)d_in[10]; const float* gv_b3 = (const float*)d_in[11];
    const float* att_w1 = (const float*)d_in[12]; const float* att_b1 = (const float*)d_in[13];
    const float* att_w2 = (const float*)d_in[14]; const float* att_b2 = (const float*)d_in[15];
    const float* att_w3 = (const float*)d_in[16]; const float* att_b3 = (const float*)d_in[17];
    const float* wr1_w  = (const float*)d_in[18]; const float* wr1_b = (const float*)d_in[19];
    const float* wr2_w  = (const float*)d_in[20]; const float* wr2_b = (const float*)d_in[21];
    (void)att_b3;  // softmax shift-invariance

    bf16*  wt     = (bf16*)d_ws;
    float* bias1p = (float*)((char*)d_ws + BIAS1P_BYTE);
    float* cq     = (float*)((char*)d_ws + CQ_BYTE);

    prep_all<<<PREP_W_BLOCKS + PREP_C_BLOCKS, 256, 0, stream>>>(
        gv_w1, gv_w2, gv_w3, att_w1, att_w2, wr1_w, wr2_w, gv_b3, att_b1,
        nodes_v, embed_i, wt, bias1p, cq);
    dense_fused<<<B_ / 2, 256, 0, stream>>>(nodes_v, neigh_u, neigh_r,
                                            embed_u, embed_i, embed_r,
                                            gv_b1, gv_b2, gv_b3, att_b2, att_w3,
                                            wr1_b, wr2_b, wt, cq, bias1p, (float*)d_out);
}